// Round 9
// baseline (2290.533 us; speedup 1.0000x reference)
//
#include <hip/hip_runtime.h>
#include <hip/hip_bf16.h>

#define N_NODES 100000
#define N_EDGES 3200000
#define IN_F 512
#define HID 64
#define OUT_F 64
#define K_HOPS 10
#define N_SCAN_BLOCKS ((N_NODES + 255) / 256)   // 391

// histogram geometry: 4 ranges of 32768 bins cover 131072 >= N_NODES
#define HIST_BLOCKS 64
#define HIST_BINS 32768
#define HIST_WORDS (HIST_BINS / 2)              // 16384 packed dual-uint16 words
#define EDGES_PER_HIST_BLOCK (N_EDGES / HIST_BLOCKS)  // 50000

// bucket geometry: 224 buckets x 448 nodes = 100352 >= N_NODES
#define NBKT 224
#define NBN  448
#define BKT_CAP 16384                            // mean 14286, sd ~120: safe
// bucketize pass
#define BKZ_BLOCKS 256
#define EDGES_PER_BKZ_BLOCK (N_EDGES / BKZ_BLOCKS)    // 12500
#define BKZ_BATCH 8192
// hop: src-quarter temporal partitioning (quarter table = 3.2MB < 4MB L2/XCD)
#define QSIZE 25000
#define HOP_BLOCKS 2048
#define HOP_WAVES (HOP_BLOCKS * 4)

typedef __attribute__((ext_vector_type(8))) short bf16x8;
typedef __attribute__((ext_vector_type(4))) float f32x4;

static __device__ __forceinline__ unsigned short f2bf(float f) {
    unsigned int u = __float_as_uint(f);
    u += 0x7FFFu + ((u >> 16) & 1u);            // round-to-nearest-even
    return (unsigned short)(u >> 16);
}
static __device__ __forceinline__ float bf2f(unsigned short s) {
    return __uint_as_float(((unsigned int)s) << 16);
}

// ---------------------------------------------------------------------------
__global__ void detect_i32_kernel(const unsigned int* ei_words, int* flag_is32) {
    int i = blockIdx.x * blockDim.x + threadIdx.x;  // 0..1023
    unsigned int w = ei_words[2 * i + 1];
    if (w != 0u) atomicOr(flag_is32, 1);
}

__global__ void __launch_bounds__(256) convert_kernel(const void* ei_raw, const int* flag_is32,
                                                      int* __restrict__ src32,
                                                      int* __restrict__ dst32) {
    int t = blockIdx.x * blockDim.x + threadIdx.x;     // 0 .. N_EDGES/2-1
    if (t >= N_EDGES / 2) return;
    if (*flag_is32) {
        const int2* ei = (const int2*)ei_raw;
        *(int2*)(src32 + 2 * t) = ei[t];
        *(int2*)(dst32 + 2 * t) = ei[N_EDGES / 2 + t];
    } else {
        const longlong2* ei = (const longlong2*)ei_raw;
        longlong2 s = ei[t];
        longlong2 d = ei[N_EDGES / 2 + t];
        *(int2*)(src32 + 2 * t) = make_int2((int)s.x, (int)s.y);
        *(int2*)(dst32 + 2 * t) = make_int2((int)d.x, (int)d.y);
    }
}

// Partial histograms of both arrays in LDS (packed dual-uint16), no global
// atomics. grid = (HIST_BLOCKS slices, 8): arr = y>>2, range = y&3.
__global__ void __launch_bounds__(256) hist_kernel(const int* __restrict__ src32,
                                                   const int* __restrict__ dst32,
                                                   unsigned int* __restrict__ partials) {
    __shared__ unsigned int cnt[HIST_WORDS];   // 64 KB
    int tid = threadIdx.x;
    for (int w = tid; w < HIST_WORDS; w += 256) cnt[w] = 0u;
    __syncthreads();

    int arr = blockIdx.y >> 2;
    int range = blockIdx.y & 3;
    unsigned lo = (unsigned)(range * HIST_BINS);
    const int* a = arr ? dst32 : src32;
    int beg = blockIdx.x * EDGES_PER_HIST_BLOCK;
    int end = beg + EDGES_PER_HIST_BLOCK;
    for (int i = beg + tid; i < end; i += 256) {
        unsigned v = (unsigned)a[i] - lo;
        if (v < HIST_BINS) atomicAdd(&cnt[v >> 1], 1u << ((v & 1u) * 16u));
    }
    __syncthreads();

    unsigned int* outp = partials + ((size_t)(blockIdx.y * HIST_BLOCKS + blockIdx.x)) * HIST_WORDS;
    for (int w = tid; w < HIST_WORDS / 4; w += 256)
        ((uint4*)outp)[w] = ((const uint4*)cnt)[w];
}

// Per-bin reduce over the 64 block-partials; one thread per packed word.
__global__ void __launch_bounds__(256) hist_scan_kernel(const unsigned int* __restrict__ partials,
                                                        float* __restrict__ dinv,
                                                        int* __restrict__ deg,
                                                        int arr) {
    int wg = blockIdx.x * blockDim.x + threadIdx.x;     // 0 .. 4*HIST_WORDS-1
    if (wg >= 4 * HIST_WORDS) return;
    int range = wg >> 14;
    int word = wg & (HIST_WORDS - 1);
    const unsigned int* base = partials + ((size_t)(arr * 4 + range) * HIST_BLOCKS) * HIST_WORDS + word;
    unsigned lo = 0, hi = 0;
    for (int b = 0; b < HIST_BLOCKS; ++b) {
        unsigned c = base[(size_t)b * HIST_WORDS];
        lo += c & 0xffffu;
        hi += c >> 16;
    }
    int v0 = range * HIST_BINS + 2 * word;
    if (v0 < N_NODES) {
        dinv[v0] = lo ? rsqrtf((float)lo) : 0.0f;
        if (deg) deg[v0] = (int)lo;
    }
    int v1 = v0 + 1;
    if (v1 < N_NODES) {
        dinv[v1] = hi ? rsqrtf((float)hi) : 0.0f;
        if (deg) deg[v1] = (int)hi;
    }
}

// --------------------------- row_start scan ---------------------------------
__global__ void block_sum_kernel(const int* __restrict__ deg, int* __restrict__ partial) {
    __shared__ int s[256];
    int t = threadIdx.x;
    int i = blockIdx.x * 256 + t;
    s[t] = (i < N_NODES) ? deg[i] : 0;
    __syncthreads();
    for (int off = 128; off >= 1; off >>= 1) {
        if (t < off) s[t] += s[t + off];
        __syncthreads();
    }
    if (t == 0) partial[blockIdx.x] = s[0];
}

__global__ void scan_partial_kernel(int* partial, int* row_start) {
    if (threadIdx.x == 0 && blockIdx.x == 0) {
        int acc = 0;
        for (int b = 0; b < N_SCAN_BLOCKS; ++b) {
            int v = partial[b];
            partial[b] = acc;
            acc += v;
        }
        row_start[N_NODES] = acc;
    }
}

__global__ void row_start_kernel(const int* __restrict__ deg, const int* __restrict__ partial,
                                 int* __restrict__ row_start) {
    __shared__ int s[256];
    int t = threadIdx.x;
    int i = blockIdx.x * 256 + t;
    int v = (i < N_NODES) ? deg[i] : 0;
    s[t] = v;
    __syncthreads();
    for (int off = 1; off < 256; off <<= 1) {
        int add = (t >= off) ? s[t - off] : 0;
        __syncthreads();
        s[t] += add;
        __syncthreads();
    }
    if (i < N_NODES) row_start[i] = s[t] - v + partial[blockIdx.x];
}

// bucket_start[b] = row_start[b*NBN]; gcur init.
__global__ void bucket_init_kernel(const int* __restrict__ row_start,
                                   int* __restrict__ bucket_start,
                                   int* __restrict__ gcur) {
    int t = blockIdx.x * blockDim.x + threadIdx.x;
    if (t <= NBKT) {
        int node = t * NBN;
        if (node > N_NODES) node = N_NODES;
        int v = row_start[node];
        bucket_start[t] = v;
        if (t < NBKT) gcur[t] = v;
    }
}

// Coarse bucketing with LDS-staged coalesced flushes. Entry = (src<<9)|dst_local.
__global__ void __launch_bounds__(256) bucketize_kernel(const int* __restrict__ src32,
                                                        const int* __restrict__ dst32,
                                                        int* __restrict__ gcur,
                                                        int* __restrict__ entries) {
    __shared__ unsigned int stag[BKZ_BATCH];     // 32 KB
    __shared__ unsigned char stagb[BKZ_BATCH];   // 8 KB
    __shared__ int cnt[256], sAr[256], ofs_l[256], gbase_l[256];

    int tid = threadIdx.x;
    int beg = blockIdx.x * EDGES_PER_BKZ_BLOCK;

    for (int bb = 0; bb < EDGES_PER_BKZ_BLOCK; bb += BKZ_BATCH) {
        int bn = min(BKZ_BATCH, EDGES_PER_BKZ_BLOCK - bb);
        cnt[tid] = 0;
        __syncthreads();

        unsigned pk[32];
#pragma unroll
        for (int j = 0; j < 32; ++j) {
            int loc = j * 256 + tid;
            pk[j] = 0xFFFFFFFFu;
            if (loc < bn) {
                int d = dst32[beg + bb + loc];
                int b = d / NBN;
                int dl = d - b * NBN;
                int off = atomicAdd(&cnt[b], 1);
                pk[j] = ((unsigned)b << 22) | ((unsigned)dl << 13) | (unsigned)off;
            }
        }
        __syncthreads();
        int c = cnt[tid];
        sAr[tid] = c;
        __syncthreads();
        for (int off = 1; off < 256; off <<= 1) {
            int add = (tid >= off) ? sAr[tid - off] : 0;
            __syncthreads();
            sAr[tid] += add;
            __syncthreads();
        }
        ofs_l[tid] = sAr[tid] - c;
        if (tid < NBKT && c > 0) gbase_l[tid] = atomicAdd(&gcur[tid], c);
        __syncthreads();

#pragma unroll
        for (int j = 0; j < 32; ++j) {
            int loc = j * 256 + tid;
            if (loc < bn && pk[j] != 0xFFFFFFFFu) {
                int s = src32[beg + bb + loc];
                int b = pk[j] >> 22;
                int dl = (pk[j] >> 13) & 511;
                int off = pk[j] & 8191;
                int pos = ofs_l[b] + off;
                stag[pos] = ((unsigned)s << 9) | (unsigned)dl;
                stagb[pos] = (unsigned char)b;
            }
        }
        __syncthreads();
        for (int i = tid; i < bn; i += 256) {
            int b = stagb[i];
            entries[gbase_l[b] + (i - ofs_l[b])] = (int)stag[i];
        }
        __syncthreads();
    }
}

// Per-bucket counting sort in LDS by key (dst_local, src_quarter):
// produces dst-sorted + quarter-sub-sorted src-only CSR, and per-node packed
// quarter offsets qoff = {o1|o2<<16, o3|deg<<16}.
#define SORT_LDS_BYTES ((2 * BKT_CAP + 1792 + 512) * 4)    // 140,288 B
__global__ void __launch_bounds__(1024) sort_kernel(const int* __restrict__ entries,
                                                    const int* __restrict__ bucket_start,
                                                    int* __restrict__ srcs,
                                                    uint2* __restrict__ qoff) {
    extern __shared__ int sbuf[];
    int* sin  = sbuf;                    // BKT_CAP
    int* sout = sbuf + BKT_CAP;          // BKT_CAP
    int* cnt  = sbuf + 2 * BKT_CAP;      // 1792
    int* nsum = cnt + 1792;              // 512
    int tid = threadIdx.x;
    int b = blockIdx.x;
    int ebeg = bucket_start[b];
    int eend = bucket_start[b + 1];
    int n = eend - ebeg;

    for (int i = tid; i < n; i += 1024) sin[i] = entries[ebeg + i];
    for (int i = tid; i < 1792; i += 1024) cnt[i] = 0;
    if (tid < 512) nsum[tid] = 0;
    __syncthreads();
    for (int i = tid; i < n; i += 1024) {
        unsigned e = (unsigned)sin[i];
        int q = (int)(e >> 9) / QSIZE;            // 0..3 (src < 100000)
        atomicAdd(&cnt[(e & 511) * 4 + q], 1);
    }
    __syncthreads();
    int s0 = 0, s1 = 0, s2 = 0, s3 = 0;
    if (tid < NBN) {
        s0 = cnt[tid * 4]; s1 = cnt[tid * 4 + 1];
        s2 = cnt[tid * 4 + 2]; s3 = cnt[tid * 4 + 3];
        nsum[tid] = s0 + s1 + s2 + s3;
    }
    __syncthreads();
    for (int off = 1; off < 512; off <<= 1) {     // Hillis-Steele inclusive
        int v = (tid < 512 && tid >= off) ? nsum[tid - off] : 0;
        __syncthreads();
        if (tid < 512) nsum[tid] += v;
        __syncthreads();
    }
    if (tid < NBN) {
        int deg = s0 + s1 + s2 + s3;
        int base = nsum[tid] - deg;               // exclusive node start
        cnt[tid * 4 + 0] = base;
        cnt[tid * 4 + 1] = base + s0;
        cnt[tid * 4 + 2] = base + s0 + s1;
        cnt[tid * 4 + 3] = base + s0 + s1 + s2;
        int node = b * NBN + tid;
        if (node < N_NODES)
            qoff[node] = make_uint2((unsigned)s0 | ((unsigned)(s0 + s1) << 16),
                                    (unsigned)(s0 + s1 + s2) | ((unsigned)deg << 16));
    }
    __syncthreads();
    for (int i = tid; i < n; i += 1024) {
        unsigned e = (unsigned)sin[i];
        int src = (int)(e >> 9);
        int q = src / QSIZE;
        int pos = atomicAdd(&cnt[(e & 511) * 4 + q], 1);
        sout[pos] = src;
    }
    __syncthreads();
    for (int i = tid; i < n; i += 1024) srcs[ebeg + i] = sout[i];
}

// ---------------------------------------------------------------------------
// MFMA MLP + fused initial combine + g0 = dinv_out * h (bf16).
__global__ void __launch_bounds__(256) mlp_kernel(const float* __restrict__ x,
                                                  const float* __restrict__ W1,
                                                  const float* __restrict__ W2,
                                                  const float* __restrict__ sv,
                                                  const float* __restrict__ dinv_out,
                                                  float* __restrict__ out,
                                                  unsigned short* __restrict__ g0) {
    __shared__ __align__(16) unsigned short b1[8 * 4 * 64 * 8];   // 32 KB [t][nt][lane][j]
    __shared__ __align__(16) unsigned short b2[2 * 4 * 64 * 8];   // 8 KB
    __shared__ __align__(16) unsigned short a2s[4][2 * 64 * 8];   // 8 KB per-wave layer2 A

    int tid = threadIdx.x;
    int w = tid >> 6;
    int l = tid & 63;
    int kg = l >> 4;
    int m  = l & 15;
    int row0 = blockIdx.x * 64;
    int row = row0 + w * 16 + m;
    bool valid = row < N_NODES;
    const float* xp = x + (size_t)row * IN_F + kg * 8;

#pragma unroll
    for (int i = 0; i < 4; ++i) {
        int flat = i * 1024 + tid * 4;
        float4 v = *(const float4*)(W2 + flat);
        int r = flat >> 6, c0 = flat & 63;
        int t2 = r >> 5, kgs = (r >> 3) & 3, ko = r & 7;
        float vv[4] = {v.x, v.y, v.z, v.w};
#pragma unroll
        for (int q = 0; q < 4; ++q) {
            int cc = c0 + q;
            b2[(((t2 * 4 + (cc >> 4)) * 64) + (kgs * 16 + (cc & 15))) * 8 + ko] = f2bf(vv[q]);
        }
    }

    f32x4 acc[4];
#pragma unroll
    for (int nt = 0; nt < 4; ++nt) acc[nt] = (f32x4){0.f, 0.f, 0.f, 0.f};

    for (int p = 0; p < 2; ++p) {
        __syncthreads();
#pragma unroll
        for (int i = 0; i < 16; ++i) {
            int flat = i * 1024 + tid * 4;
            int rl = flat >> 6;
            int c0 = flat & 63;
            float4 v = *(const float4*)(W1 + (size_t)(p * 256 + rl) * HID + c0);
            int t = rl >> 5, kgs = (rl >> 3) & 3, ko = rl & 7;
            float vv[4] = {v.x, v.y, v.z, v.w};
#pragma unroll
            for (int q = 0; q < 4; ++q) {
                int cc = c0 + q;
                b1[(((t * 4 + (cc >> 4)) * 64) + (kgs * 16 + (cc & 15))) * 8 + ko] = f2bf(vv[q]);
            }
        }
        __syncthreads();
#pragma unroll
        for (int t = 0; t < 8; ++t) {
            union { bf16x8 v; unsigned short u[8]; } a;
            if (valid) {
                const float* ap = xp + (p * 256 + t * 32);
                float4 u0 = *(const float4*)ap;
                float4 u1 = *(const float4*)(ap + 4);
                a.u[0] = f2bf(u0.x); a.u[1] = f2bf(u0.y);
                a.u[2] = f2bf(u0.z); a.u[3] = f2bf(u0.w);
                a.u[4] = f2bf(u1.x); a.u[5] = f2bf(u1.y);
                a.u[6] = f2bf(u1.z); a.u[7] = f2bf(u1.w);
            } else {
#pragma unroll
                for (int q = 0; q < 8; ++q) a.u[q] = 0;
            }
#pragma unroll
            for (int nt = 0; nt < 4; ++nt) {
                bf16x8 b = *(const bf16x8*)&b1[((t * 4 + nt) * 64 + l) * 8];
                acc[nt] = __builtin_amdgcn_mfma_f32_16x16x32_bf16(a.v, b, acc[nt], 0, 0, 0);
            }
        }
    }

#pragma unroll
    for (int nt = 0; nt < 4; ++nt) {
#pragma unroll
        for (int reg = 0; reg < 4; ++reg) {
            float v = fmaxf(acc[nt][reg], 0.0f);
            int cc = nt * 16 + m;
            int r = kg * 4 + reg;
            a2s[w][((cc >> 5) * 64 + (((cc >> 3) & 3) * 16 + r)) * 8 + (cc & 7)] = f2bf(v);
        }
    }

    f32x4 acc2[4];
#pragma unroll
    for (int nt = 0; nt < 4; ++nt) acc2[nt] = (f32x4){0.f, 0.f, 0.f, 0.f};
#pragma unroll
    for (int t2 = 0; t2 < 2; ++t2) {
        bf16x8 a = *(const bf16x8*)&a2s[w][(t2 * 64 + l) * 8];
#pragma unroll
        for (int nt = 0; nt < 4; ++nt) {
            bf16x8 b = *(const bf16x8*)&b2[((t2 * 4 + nt) * 64 + l) * 8];
            acc2[nt] = __builtin_amdgcn_mfma_f32_16x16x32_bf16(a, b, acc2[nt], 0, 0, 0);
        }
    }

    // fused epilogue: relu, gate, out init, g0
    float vals[4][4];
    float pr[4] = {0.f, 0.f, 0.f, 0.f};
#pragma unroll
    for (int nt = 0; nt < 4; ++nt) {
        float s_c = sv[nt * 16 + m];
#pragma unroll
        for (int reg = 0; reg < 4; ++reg) {
            float v = fmaxf(acc2[nt][reg], 0.0f);
            vals[nt][reg] = v;
            pr[reg] = fmaf(v, s_c, pr[reg]);
        }
    }
#pragma unroll
    for (int off = 1; off <= 8; off <<= 1) {
#pragma unroll
        for (int reg = 0; reg < 4; ++reg) pr[reg] += __shfl_xor(pr[reg], off, 64);
    }
#pragma unroll
    for (int reg = 0; reg < 4; ++reg) {
        int node = row0 + w * 16 + kg * 4 + reg;
        if (node < N_NODES) {
            float score = 1.0f / (1.0f + expf(-pr[reg]));
            float dv = dinv_out[node];
#pragma unroll
            for (int nt = 0; nt < 4; ++nt) {
                out[(size_t)node * OUT_F + nt * 16 + m] = score * vals[nt][reg];
                g0[(size_t)node * OUT_F + nt * 16 + m] = f2bf(dv * vals[nt][reg]);
            }
        }
    }
}

// ---------------------------------------------------------------------------
// One hop, src-quarter pass-major. 2048 persistent blocks; wave per node-visit.
// Pass q touches only srcs in [q*25000,(q+1)*25000) -> 3.2MB working set/XCD.
// Quarter partials RMW a global f32 acc buffer; pass 3 fuses the epilogue.
__global__ void __launch_bounds__(256) hop_kernel(
        const unsigned short* __restrict__ g_prev,
        const int* __restrict__ row_start,
        const int* __restrict__ srcs,
        const uint2* __restrict__ qoff,
        const float* __restrict__ dinv_in,
        const float* __restrict__ dinv_out,
        const float* __restrict__ sv,
        float* __restrict__ accbuf,
        unsigned short* __restrict__ g_next,
        float* __restrict__ out) {
    int lane = threadIdx.x & 63;
    int wid = blockIdx.x * 4 + (threadIdx.x >> 6);
    int slot = lane >> 3;    // 0..7: edge slot
    int sub  = lane & 7;     // feature group: features 8*sub..8*sub+7

#pragma unroll
    for (int q = 0; q < 4; ++q) {
        for (int node = wid; node < N_NODES; node += HOP_WAVES) {
            int beg = row_start[node];
            uint2 qo = qoff[node];
            int o1 = (int)(qo.x & 0xffffu), o2 = (int)(qo.x >> 16);
            int o3 = (int)(qo.y & 0xffffu), dg = (int)(qo.y >> 16);
            int lo = (q == 0) ? 0 : (q == 1) ? o1 : (q == 2) ? o2 : o3;
            int hi = (q == 0) ? o1 : (q == 1) ? o2 : (q == 2) ? o3 : dg;
            int qb = beg + lo, qe = beg + hi;

            float acc[8];
#pragma unroll
            for (int j = 0; j < 8; ++j) acc[j] = 0.0f;

            for (int chunk = qb; chunk < qe; chunk += 64) {
                int nrem = qe - chunk;                    // wave-uniform
                int es = (chunk + lane < qe) ? srcs[chunk + lane] : 0;
                uint4 v[8];
#pragma unroll
                for (int g = 0; g < 8; ++g) {
                    int s = __shfl(es, g * 8 + slot, 64);
                    if (g * 8 + slot < nrem)
                        v[g] = *(const uint4*)(g_prev + (size_t)s * OUT_F + sub * 8);
                }
#pragma unroll
                for (int g = 0; g < 8; ++g) {
                    if (g * 8 + slot < nrem) {
                        acc[0] += __uint_as_float(v[g].x << 16);
                        acc[1] += __uint_as_float(v[g].x & 0xffff0000u);
                        acc[2] += __uint_as_float(v[g].y << 16);
                        acc[3] += __uint_as_float(v[g].y & 0xffff0000u);
                        acc[4] += __uint_as_float(v[g].z << 16);
                        acc[5] += __uint_as_float(v[g].z & 0xffff0000u);
                        acc[6] += __uint_as_float(v[g].w << 16);
                        acc[7] += __uint_as_float(v[g].w & 0xffff0000u);
                    }
                }
            }
#pragma unroll
            for (int off = 8; off <= 32; off <<= 1) {
#pragma unroll
                for (int j = 0; j < 8; ++j) acc[j] += __shfl_xor(acc[j], off, 64);
            }

            if (slot == 0) {
                float* ap = accbuf + (size_t)node * OUT_F + sub * 8;
                if (q == 0) {
                    float4 w0 = make_float4(acc[0], acc[1], acc[2], acc[3]);
                    float4 w1 = make_float4(acc[4], acc[5], acc[6], acc[7]);
                    ((float4*)ap)[0] = w0;
                    ((float4*)ap)[1] = w1;
                } else if (q < 3) {
                    float4 r0 = ((const float4*)ap)[0];
                    float4 r1 = ((const float4*)ap)[1];
                    r0.x += acc[0]; r0.y += acc[1]; r0.z += acc[2]; r0.w += acc[3];
                    r1.x += acc[4]; r1.y += acc[5]; r1.z += acc[6]; r1.w += acc[7];
                    ((float4*)ap)[0] = r0;
                    ((float4*)ap)[1] = r1;
                } else {
                    float4 r0 = ((const float4*)ap)[0];
                    float4 r1 = ((const float4*)ap)[1];
                    float tot[8] = {r0.x + acc[0], r0.y + acc[1], r0.z + acc[2], r0.w + acc[3],
                                    r1.x + acc[4], r1.y + acc[5], r1.z + acc[6], r1.w + acc[7]};
                    float di = dinv_in[node];
                    float dq_ = dinv_out[node];
                    float fn[8];
#pragma unroll
                    for (int j = 0; j < 8; ++j) fn[j] = di * tot[j];
                    float4 s0 = *(const float4*)(sv + sub * 8);
                    float4 s1 = *(const float4*)(sv + sub * 8 + 4);
                    float p = fn[0] * s0.x + fn[1] * s0.y + fn[2] * s0.z + fn[3] * s0.w
                            + fn[4] * s1.x + fn[5] * s1.y + fn[6] * s1.z + fn[7] * s1.w;
#pragma unroll
                    for (int off = 1; off <= 4; off <<= 1) p += __shfl_xor(p, off, 64);
                    float score = 1.0f / (1.0f + expf(-p));

                    float4* op = (float4*)(out + (size_t)node * OUT_F + sub * 8);
                    float4 o0 = op[0], o1v = op[1];
                    o0.x = fmaf(score, fn[0], o0.x);
                    o0.y = fmaf(score, fn[1], o0.y);
                    o0.z = fmaf(score, fn[2], o0.z);
                    o0.w = fmaf(score, fn[3], o0.w);
                    o1v.x = fmaf(score, fn[4], o1v.x);
                    o1v.y = fmaf(score, fn[5], o1v.y);
                    o1v.z = fmaf(score, fn[6], o1v.z);
                    o1v.w = fmaf(score, fn[7], o1v.w);
                    op[0] = o0;
                    op[1] = o1v;

                    uint4 wv;
                    wv.x = (unsigned)f2bf(dq_ * fn[0]) | ((unsigned)f2bf(dq_ * fn[1]) << 16);
                    wv.y = (unsigned)f2bf(dq_ * fn[2]) | ((unsigned)f2bf(dq_ * fn[3]) << 16);
                    wv.z = (unsigned)f2bf(dq_ * fn[4]) | ((unsigned)f2bf(dq_ * fn[5]) << 16);
                    wv.w = (unsigned)f2bf(dq_ * fn[6]) | ((unsigned)f2bf(dq_ * fn[7]) << 16);
                    *(uint4*)(g_next + (size_t)node * OUT_F + sub * 8) = wv;
                }
            }
        }
    }
}

// ---------------------------------------------------------------------------
extern "C" void kernel_launch(void* const* d_in, const int* in_sizes, int n_in,
                              void* d_out, int out_size, void* d_ws, size_t ws_size,
                              hipStream_t stream) {
    const float* x  = (const float*)d_in[0];
    const void*  ei = d_in[1];
    const float* W1 = (const float*)d_in[2];
    const float* W2 = (const float*)d_in[3];
    const float* sv = (const float*)d_in[4];
    float* out = (float*)d_out;

    char* p = (char*)d_ws;
    auto alloc = [&](size_t bytes) -> char* {
        char* r = p;
        p += (bytes + 255) & ~(size_t)255;
        return r;
    };
    unsigned short* gA = (unsigned short*)alloc(sizeof(unsigned short) * N_NODES * OUT_F);
    unsigned short* gB = (unsigned short*)alloc(sizeof(unsigned short) * N_NODES * OUT_F);
    int*   src32     = (int*)alloc(sizeof(int) * N_EDGES);
    int*   dst32     = (int*)alloc(sizeof(int) * N_EDGES);
    // partials (33.5 MB) dead after hist_scans; entries_raw (12.8 MB) then
    // the hop acc buffer (25.7 MB f32) alias the same region in sequence.
    char*  shared_region = alloc(sizeof(unsigned int) * 8 * HIST_BLOCKS * HIST_WORDS);
    unsigned int* partials = (unsigned int*)shared_region;
    int*   entries_raw = (int*)shared_region;
    float* accbuf    = (float*)shared_region;
    int*   srcs      = (int*)alloc(sizeof(int) * N_EDGES);                      // 12.8 MB
    uint2* qoff      = (uint2*)alloc(sizeof(uint2) * (size_t)NBKT * NBN);       // 0.8 MB
    int*   deg_in    = (int*)alloc(sizeof(int) * N_NODES);
    float* dinv_out  = (float*)alloc(sizeof(float) * N_NODES);
    float* dinv_in   = (float*)alloc(sizeof(float) * N_NODES);
    int*   row_start = (int*)alloc(sizeof(int) * (N_NODES + 1));
    int*   bucket_start = (int*)alloc(sizeof(int) * (NBKT + 1));
    int*   gcur      = (int*)alloc(sizeof(int) * NBKT);
    int*   partial   = (int*)alloc(sizeof(int) * N_SCAN_BLOCKS);
    int*   flag      = (int*)alloc(256);

    hipMemsetAsync(flag, 0, sizeof(int), stream);

    detect_i32_kernel<<<4, 256, 0, stream>>>((const unsigned int*)ei, flag);
    convert_kernel<<<(N_EDGES / 2 + 255) / 256, 256, 0, stream>>>(ei, flag, src32, dst32);

    hist_kernel<<<dim3(HIST_BLOCKS, 8), 256, 0, stream>>>(src32, dst32, partials);
    hist_scan_kernel<<<(4 * HIST_WORDS + 255) / 256, 256, 0, stream>>>(partials, dinv_out,
                                                                       nullptr, 0);
    hist_scan_kernel<<<(4 * HIST_WORDS + 255) / 256, 256, 0, stream>>>(partials, dinv_in,
                                                                       deg_in, 1);
    block_sum_kernel<<<N_SCAN_BLOCKS, 256, 0, stream>>>(deg_in, partial);
    scan_partial_kernel<<<1, 64, 0, stream>>>(partial, row_start);
    row_start_kernel<<<N_SCAN_BLOCKS, 256, 0, stream>>>(deg_in, partial, row_start);
    bucket_init_kernel<<<1, 256, 0, stream>>>(row_start, bucket_start, gcur);
    bucketize_kernel<<<BKZ_BLOCKS, 256, 0, stream>>>(src32, dst32, gcur, entries_raw);

    hipFuncSetAttribute((const void*)sort_kernel,
                        hipFuncAttributeMaxDynamicSharedMemorySize, SORT_LDS_BYTES);
    sort_kernel<<<NBKT, 1024, SORT_LDS_BYTES, stream>>>(entries_raw, bucket_start, srcs, qoff);

    int mlp_blocks = (N_NODES + 63) / 64;                   // 1563
    mlp_kernel<<<mlp_blocks, 256, 0, stream>>>(x, W1, W2, sv, dinv_out, out, gA);

    unsigned short* cur = gA;
    unsigned short* nxt = gB;
    for (int hop = 0; hop < K_HOPS; ++hop) {
        hop_kernel<<<HOP_BLOCKS, 256, 0, stream>>>(cur, row_start, srcs, qoff,
                                                   dinv_in, dinv_out, sv,
                                                   accbuf, nxt, out);
        unsigned short* t = cur; cur = nxt; nxt = t;
    }
}

// Round 10
// 841.173 us; speedup vs baseline: 2.7230x; 2.7230x over previous
//
#include <hip/hip_runtime.h>
#include <hip/hip_bf16.h>

#define N_NODES 100000
#define N_EDGES 3200000
#define IN_F 512
#define HID 64
#define OUT_F 64
#define K_HOPS 10

// src histogram geometry: 4 ranges of 32768 bins cover 131072 >= N_NODES
#define HIST_BLOCKS 64
#define HIST_BINS 32768
#define HIST_WORDS (HIST_BINS / 2)              // 16384 packed dual-uint16 words
#define EDGES_PER_HIST_BLOCK (N_EDGES / HIST_BLOCKS)  // 50000

// bucket geometry: 224 buckets x 448 nodes = 100352 >= N_NODES
#define NBKT 224
#define NBN  448
#define BKT_CAP 16384                            // mean 14286, sd ~120: safe
// bucketize pass
#define BKZ_BLOCKS 256
#define EDGES_PER_BKZ_BLOCK (N_EDGES / BKZ_BLOCKS)    // 12500
#define BKZ_BATCH 8192

typedef __attribute__((ext_vector_type(8))) short bf16x8;
typedef __attribute__((ext_vector_type(4))) float f32x4;

static __device__ __forceinline__ unsigned short f2bf(float f) {
    unsigned int u = __float_as_uint(f);
    u += 0x7FFFu + ((u >> 16) & 1u);            // round-to-nearest-even
    return (unsigned short)(u >> 16);
}
static __device__ __forceinline__ float bf2f(unsigned short s) {
    return __uint_as_float(((unsigned int)s) << 16);
}

// ---------------------------------------------------------------------------
__global__ void detect_i32_kernel(const unsigned int* ei_words, int* flag_is32) {
    int i = blockIdx.x * blockDim.x + threadIdx.x;  // 0..1023
    unsigned int w = ei_words[2 * i + 1];
    if (w != 0u) atomicOr(flag_is32, 1);
}

__global__ void __launch_bounds__(256) convert_kernel(const void* ei_raw, const int* flag_is32,
                                                      int* __restrict__ src32,
                                                      int* __restrict__ dst32) {
    int t = blockIdx.x * blockDim.x + threadIdx.x;     // 0 .. N_EDGES/2-1
    if (t >= N_EDGES / 2) return;
    if (*flag_is32) {
        const int2* ei = (const int2*)ei_raw;
        *(int2*)(src32 + 2 * t) = ei[t];
        *(int2*)(dst32 + 2 * t) = ei[N_EDGES / 2 + t];
    } else {
        const longlong2* ei = (const longlong2*)ei_raw;
        longlong2 s = ei[t];
        longlong2 d = ei[N_EDGES / 2 + t];
        *(int2*)(src32 + 2 * t) = make_int2((int)s.x, (int)s.y);
        *(int2*)(dst32 + 2 * t) = make_int2((int)d.x, (int)d.y);
    }
}

// Partial histograms of the src array in LDS (packed dual-uint16).
// grid = (HIST_BLOCKS slices, 4 ranges).
__global__ void __launch_bounds__(256) hist_kernel(const int* __restrict__ a,
                                                   unsigned int* __restrict__ partials) {
    __shared__ unsigned int cnt[HIST_WORDS];   // 64 KB
    int tid = threadIdx.x;
    for (int w = tid; w < HIST_WORDS; w += 256) cnt[w] = 0u;
    __syncthreads();

    int range = blockIdx.y;
    unsigned lo = (unsigned)(range * HIST_BINS);
    int beg = blockIdx.x * EDGES_PER_HIST_BLOCK;
    int end = beg + EDGES_PER_HIST_BLOCK;
    for (int i = beg + tid; i < end; i += 256) {
        unsigned v = (unsigned)a[i] - lo;
        if (v < HIST_BINS) atomicAdd(&cnt[v >> 1], 1u << ((v & 1u) * 16u));
    }
    __syncthreads();

    unsigned int* outp = partials + ((size_t)(blockIdx.y * HIST_BLOCKS + blockIdx.x)) * HIST_WORDS;
    for (int w = tid; w < HIST_WORDS / 4; w += 256)
        ((uint4*)outp)[w] = ((const uint4*)cnt)[w];
}

// Per-bin reduce over the 64 block-partials -> dinv_out.
__global__ void __launch_bounds__(256) hist_scan_kernel(const unsigned int* __restrict__ partials,
                                                        float* __restrict__ dinv) {
    int wg = blockIdx.x * blockDim.x + threadIdx.x;     // 0 .. 4*HIST_WORDS-1
    if (wg >= 4 * HIST_WORDS) return;
    int range = wg >> 14;
    int word = wg & (HIST_WORDS - 1);
    const unsigned int* base = partials + ((size_t)range * HIST_BLOCKS) * HIST_WORDS + word;
    unsigned lo = 0, hi = 0;
    for (int b = 0; b < HIST_BLOCKS; ++b) {
        unsigned c = base[(size_t)b * HIST_WORDS];
        lo += c & 0xffffu;
        hi += c >> 16;
    }
    int v0 = range * HIST_BINS + 2 * word;
    if (v0 < N_NODES) dinv[v0] = lo ? rsqrtf((float)lo) : 0.0f;
    int v1 = v0 + 1;
    if (v1 < N_NODES) dinv[v1] = hi ? rsqrtf((float)hi) : 0.0f;
}

// 224-bin per-bucket edge count (cheap; global atomics on only 224 bins).
__global__ void __launch_bounds__(256) bucket_cnt_kernel(const int* __restrict__ dst32,
                                                         int* __restrict__ bucket_cnt) {
    __shared__ int c[NBKT];
    int tid = threadIdx.x;
    if (tid < NBKT) c[tid] = 0;
    __syncthreads();
    int beg = blockIdx.x * EDGES_PER_BKZ_BLOCK;
    int end = beg + EDGES_PER_BKZ_BLOCK;
    for (int i = beg + tid; i < end; i += 256) {
        atomicAdd(&c[dst32[i] / NBN], 1);
    }
    __syncthreads();
    if (tid < NBKT && c[tid] > 0) atomicAdd(&bucket_cnt[tid], c[tid]);
}

// Scan bucket counts -> bucket_start[NBKT+1], gcur; also row_start[N]=E.
__global__ void __launch_bounds__(256) bucket_scan_kernel(const int* __restrict__ bucket_cnt,
                                                          int* __restrict__ bucket_start,
                                                          int* __restrict__ gcur,
                                                          int* __restrict__ row_start) {
    __shared__ int s[256];
    int t = threadIdx.x;
    int c = (t < NBKT) ? bucket_cnt[t] : 0;
    s[t] = c;
    __syncthreads();
    for (int off = 1; off < 256; off <<= 1) {
        int add = (t >= off) ? s[t - off] : 0;
        __syncthreads();
        s[t] += add;
        __syncthreads();
    }
    if (t < NBKT) {
        int excl = s[t] - c;
        bucket_start[t] = excl;
        gcur[t] = excl;
        if (t == NBKT - 1) {
            bucket_start[NBKT] = s[t];
            row_start[N_NODES] = s[t];
        }
    }
}

// Coarse bucketing with LDS-staged coalesced flushes. Entry = (src<<9)|dst_local.
__global__ void __launch_bounds__(256) bucketize_kernel(const int* __restrict__ src32,
                                                        const int* __restrict__ dst32,
                                                        int* __restrict__ gcur,
                                                        int* __restrict__ entries) {
    __shared__ unsigned int stag[BKZ_BATCH];     // 32 KB
    __shared__ unsigned char stagb[BKZ_BATCH];   // 8 KB
    __shared__ int cnt[256], sAr[256], ofs_l[256], gbase_l[256];

    int tid = threadIdx.x;
    int beg = blockIdx.x * EDGES_PER_BKZ_BLOCK;

    for (int bb = 0; bb < EDGES_PER_BKZ_BLOCK; bb += BKZ_BATCH) {
        int bn = min(BKZ_BATCH, EDGES_PER_BKZ_BLOCK - bb);
        cnt[tid] = 0;
        __syncthreads();

        unsigned pk[32];
#pragma unroll
        for (int j = 0; j < 32; ++j) {
            int loc = j * 256 + tid;
            pk[j] = 0xFFFFFFFFu;
            if (loc < bn) {
                int d = dst32[beg + bb + loc];
                int b = d / NBN;
                int dl = d - b * NBN;
                int off = atomicAdd(&cnt[b], 1);
                pk[j] = ((unsigned)b << 22) | ((unsigned)dl << 13) | (unsigned)off;
            }
        }
        __syncthreads();
        int c = cnt[tid];
        sAr[tid] = c;
        __syncthreads();
        for (int off = 1; off < 256; off <<= 1) {
            int add = (tid >= off) ? sAr[tid - off] : 0;
            __syncthreads();
            sAr[tid] += add;
            __syncthreads();
        }
        ofs_l[tid] = sAr[tid] - c;
        if (tid < NBKT && c > 0) gbase_l[tid] = atomicAdd(&gcur[tid], c);
        __syncthreads();

#pragma unroll
        for (int j = 0; j < 32; ++j) {
            int loc = j * 256 + tid;
            if (loc < bn && pk[j] != 0xFFFFFFFFu) {
                int s = src32[beg + bb + loc];
                int b = pk[j] >> 22;
                int dl = (pk[j] >> 13) & 511;
                int off = pk[j] & 8191;
                int pos = ofs_l[b] + off;
                stag[pos] = ((unsigned)s << 9) | (unsigned)dl;
                stagb[pos] = (unsigned char)b;
            }
        }
        __syncthreads();
        for (int i = tid; i < bn; i += 256) {
            int b = stagb[i];
            entries[gbase_l[b] + (i - ofs_l[b])] = (int)stag[i];
        }
        __syncthreads();
    }
}

// Per-bucket counting sort in LDS: produces dst-sorted src-only CSR and
// writes row_start + dinv_in for its 448 nodes (no global scan needed).
#define SORT_LDS_BYTES ((2 * BKT_CAP + 512 + 512) * 4)    // 135,168 B
__global__ void __launch_bounds__(1024) sort_kernel(const int* __restrict__ entries,
                                                    const int* __restrict__ bucket_start,
                                                    int* __restrict__ srcs,
                                                    int* __restrict__ row_start,
                                                    float* __restrict__ dinv_in) {
    extern __shared__ int sbuf[];
    int* sin  = sbuf;                    // BKT_CAP
    int* sout = sbuf + BKT_CAP;          // BKT_CAP
    int* cnt  = sbuf + 2 * BKT_CAP;      // 512
    int* nsum = cnt + 512;               // 512
    int tid = threadIdx.x;
    int b = blockIdx.x;
    int ebeg = bucket_start[b];
    int eend = bucket_start[b + 1];
    int n = eend - ebeg;

    for (int i = tid; i < n; i += 1024) sin[i] = entries[ebeg + i];
    if (tid < 512) { cnt[tid] = 0; nsum[tid] = 0; }
    __syncthreads();
    for (int i = tid; i < n; i += 1024) {
        atomicAdd(&cnt[(unsigned)sin[i] & 511u], 1);
    }
    __syncthreads();
    int c = (tid < 512) ? cnt[tid] : 0;
    if (tid < 512) nsum[tid] = c;
    __syncthreads();
    for (int off = 1; off < 512; off <<= 1) {     // Hillis-Steele inclusive
        int v = (tid < 512 && tid >= off) ? nsum[tid - off] : 0;
        __syncthreads();
        if (tid < 512) nsum[tid] += v;
        __syncthreads();
    }
    if (tid < NBN) {
        int excl = nsum[tid] - c;
        cnt[tid] = excl;                          // reuse as cursor
        int node = b * NBN + tid;
        if (node < N_NODES) {
            row_start[node] = ebeg + excl;
            dinv_in[node] = c ? rsqrtf((float)c) : 0.0f;
        }
    }
    __syncthreads();
    for (int i = tid; i < n; i += 1024) {
        unsigned e = (unsigned)sin[i];
        int pos = atomicAdd(&cnt[e & 511u], 1);
        sout[pos] = (int)(e >> 9);
    }
    __syncthreads();
    for (int i = tid; i < n; i += 1024) srcs[ebeg + i] = sout[i];
}

// ---------------------------------------------------------------------------
// MFMA MLP + fused initial combine + g0 = dinv_out * h (bf16).
__global__ void __launch_bounds__(256) mlp_kernel(const float* __restrict__ x,
                                                  const float* __restrict__ W1,
                                                  const float* __restrict__ W2,
                                                  const float* __restrict__ sv,
                                                  const float* __restrict__ dinv_out,
                                                  float* __restrict__ out,
                                                  unsigned short* __restrict__ g0) {
    __shared__ __align__(16) unsigned short b1[8 * 4 * 64 * 8];   // 32 KB [t][nt][lane][j]
    __shared__ __align__(16) unsigned short b2[2 * 4 * 64 * 8];   // 8 KB
    __shared__ __align__(16) unsigned short a2s[4][2 * 64 * 8];   // 8 KB per-wave layer2 A

    int tid = threadIdx.x;
    int w = tid >> 6;
    int l = tid & 63;
    int kg = l >> 4;
    int m  = l & 15;
    int row0 = blockIdx.x * 64;
    int row = row0 + w * 16 + m;
    bool valid = row < N_NODES;
    const float* xp = x + (size_t)row * IN_F + kg * 8;

#pragma unroll
    for (int i = 0; i < 4; ++i) {
        int flat = i * 1024 + tid * 4;
        float4 v = *(const float4*)(W2 + flat);
        int r = flat >> 6, c0 = flat & 63;
        int t2 = r >> 5, kgs = (r >> 3) & 3, ko = r & 7;
        float vv[4] = {v.x, v.y, v.z, v.w};
#pragma unroll
        for (int q = 0; q < 4; ++q) {
            int cc = c0 + q;
            b2[(((t2 * 4 + (cc >> 4)) * 64) + (kgs * 16 + (cc & 15))) * 8 + ko] = f2bf(vv[q]);
        }
    }

    f32x4 acc[4];
#pragma unroll
    for (int nt = 0; nt < 4; ++nt) acc[nt] = (f32x4){0.f, 0.f, 0.f, 0.f};

    for (int p = 0; p < 2; ++p) {
        __syncthreads();
#pragma unroll
        for (int i = 0; i < 16; ++i) {
            int flat = i * 1024 + tid * 4;
            int rl = flat >> 6;
            int c0 = flat & 63;
            float4 v = *(const float4*)(W1 + (size_t)(p * 256 + rl) * HID + c0);
            int t = rl >> 5, kgs = (rl >> 3) & 3, ko = rl & 7;
            float vv[4] = {v.x, v.y, v.z, v.w};
#pragma unroll
            for (int q = 0; q < 4; ++q) {
                int cc = c0 + q;
                b1[(((t * 4 + (cc >> 4)) * 64) + (kgs * 16 + (cc & 15))) * 8 + ko] = f2bf(vv[q]);
            }
        }
        __syncthreads();
#pragma unroll
        for (int t = 0; t < 8; ++t) {
            union { bf16x8 v; unsigned short u[8]; } a;
            if (valid) {
                const float* ap = xp + (p * 256 + t * 32);
                float4 u0 = *(const float4*)ap;
                float4 u1 = *(const float4*)(ap + 4);
                a.u[0] = f2bf(u0.x); a.u[1] = f2bf(u0.y);
                a.u[2] = f2bf(u0.z); a.u[3] = f2bf(u0.w);
                a.u[4] = f2bf(u1.x); a.u[5] = f2bf(u1.y);
                a.u[6] = f2bf(u1.z); a.u[7] = f2bf(u1.w);
            } else {
#pragma unroll
                for (int q = 0; q < 8; ++q) a.u[q] = 0;
            }
#pragma unroll
            for (int nt = 0; nt < 4; ++nt) {
                bf16x8 b = *(const bf16x8*)&b1[((t * 4 + nt) * 64 + l) * 8];
                acc[nt] = __builtin_amdgcn_mfma_f32_16x16x32_bf16(a.v, b, acc[nt], 0, 0, 0);
            }
        }
    }

#pragma unroll
    for (int nt = 0; nt < 4; ++nt) {
#pragma unroll
        for (int reg = 0; reg < 4; ++reg) {
            float v = fmaxf(acc[nt][reg], 0.0f);
            int cc = nt * 16 + m;
            int r = kg * 4 + reg;
            a2s[w][((cc >> 5) * 64 + (((cc >> 3) & 3) * 16 + r)) * 8 + (cc & 7)] = f2bf(v);
        }
    }

    f32x4 acc2[4];
#pragma unroll
    for (int nt = 0; nt < 4; ++nt) acc2[nt] = (f32x4){0.f, 0.f, 0.f, 0.f};
#pragma unroll
    for (int t2 = 0; t2 < 2; ++t2) {
        bf16x8 a = *(const bf16x8*)&a2s[w][(t2 * 64 + l) * 8];
#pragma unroll
        for (int nt = 0; nt < 4; ++nt) {
            bf16x8 b = *(const bf16x8*)&b2[((t2 * 4 + nt) * 64 + l) * 8];
            acc2[nt] = __builtin_amdgcn_mfma_f32_16x16x32_bf16(a, b, acc2[nt], 0, 0, 0);
        }
    }

    // fused epilogue: relu, gate, out init, g0
    float vals[4][4];
    float pr[4] = {0.f, 0.f, 0.f, 0.f};
#pragma unroll
    for (int nt = 0; nt < 4; ++nt) {
        float s_c = sv[nt * 16 + m];
#pragma unroll
        for (int reg = 0; reg < 4; ++reg) {
            float v = fmaxf(acc2[nt][reg], 0.0f);
            vals[nt][reg] = v;
            pr[reg] = fmaf(v, s_c, pr[reg]);
        }
    }
#pragma unroll
    for (int off = 1; off <= 8; off <<= 1) {
#pragma unroll
        for (int reg = 0; reg < 4; ++reg) pr[reg] += __shfl_xor(pr[reg], off, 64);
    }
#pragma unroll
    for (int reg = 0; reg < 4; ++reg) {
        int node = row0 + w * 16 + kg * 4 + reg;
        if (node < N_NODES) {
            float score = 1.0f / (1.0f + expf(-pr[reg]));
            float dv = dinv_out[node];
#pragma unroll
            for (int nt = 0; nt < 4; ++nt) {
                out[(size_t)node * OUT_F + nt * 16 + m] = score * vals[nt][reg];
                g0[(size_t)node * OUT_F + nt * 16 + m] = f2bf(dv * vals[nt][reg]);
            }
        }
    }
}

// ---------------------------------------------------------------------------
// One hop + fused gate-combine (round-8 structure, measured ~60us/hop).
// One wave per dst node; src-only sorted CSR; 8 independent gathers in flight.
// g carries dinv_out-folded features: S = sum g[src]; fn = dinv_in*S;
// out += sigmoid(fn.s)*fn; g_next = dinv_out*fn.
__global__ void __launch_bounds__(256) hop_kernel(
        const unsigned short* __restrict__ g_prev,
        const int* __restrict__ row_start,
        const int* __restrict__ srcs,
        const float* __restrict__ dinv_in,
        const float* __restrict__ dinv_out,
        const float* __restrict__ sv,
        unsigned short* __restrict__ g_next,
        float* __restrict__ out) {
    int lane = threadIdx.x & 63;
    int node = blockIdx.x * 4 + (threadIdx.x >> 6);
    if (node >= N_NODES) return;
    int beg = row_start[node];
    int end = row_start[node + 1];
    int slot = lane >> 3;    // 0..7: edge slot
    int sub  = lane & 7;     // feature group: features 8*sub..8*sub+7

    float acc[8];
#pragma unroll
    for (int j = 0; j < 8; ++j) acc[j] = 0.0f;

    for (int chunk = beg; chunk < end; chunk += 64) {
        int nrem = end - chunk;                       // wave-uniform
        int es = (chunk + lane < end) ? srcs[chunk + lane] : 0;  // coalesced 256B

        uint4 v[8];
#pragma unroll
        for (int g = 0; g < 8; ++g) {
            int s = __shfl(es, g * 8 + slot, 64);
            if (g * 8 + slot < nrem)
                v[g] = *(const uint4*)(g_prev + (size_t)s * OUT_F + sub * 8);
        }
#pragma unroll
        for (int g = 0; g < 8; ++g) {
            if (g * 8 + slot < nrem) {
                acc[0] += __uint_as_float(v[g].x << 16);
                acc[1] += __uint_as_float(v[g].x & 0xffff0000u);
                acc[2] += __uint_as_float(v[g].y << 16);
                acc[3] += __uint_as_float(v[g].y & 0xffff0000u);
                acc[4] += __uint_as_float(v[g].z << 16);
                acc[5] += __uint_as_float(v[g].z & 0xffff0000u);
                acc[6] += __uint_as_float(v[g].w << 16);
                acc[7] += __uint_as_float(v[g].w & 0xffff0000u);
            }
        }
    }
#pragma unroll
    for (int off = 8; off <= 32; off <<= 1) {
#pragma unroll
        for (int j = 0; j < 8; ++j) acc[j] += __shfl_xor(acc[j], off, 64);
    }
    float di = dinv_in[node];
    float dq = dinv_out[node];
    float fn[8];
#pragma unroll
    for (int j = 0; j < 8; ++j) fn[j] = di * acc[j];

    float4 s0 = *(const float4*)(sv + sub * 8);
    float4 s1 = *(const float4*)(sv + sub * 8 + 4);
    float p = fn[0] * s0.x + fn[1] * s0.y + fn[2] * s0.z + fn[3] * s0.w
            + fn[4] * s1.x + fn[5] * s1.y + fn[6] * s1.z + fn[7] * s1.w;
#pragma unroll
    for (int off = 1; off <= 4; off <<= 1) p += __shfl_xor(p, off, 64);
    float score = 1.0f / (1.0f + expf(-p));

    if (slot == 0) {          // lanes 0..7: write g_next row (bf16, 128B)
        uint4 wv;
        wv.x = (unsigned)f2bf(dq * fn[0]) | ((unsigned)f2bf(dq * fn[1]) << 16);
        wv.y = (unsigned)f2bf(dq * fn[2]) | ((unsigned)f2bf(dq * fn[3]) << 16);
        wv.z = (unsigned)f2bf(dq * fn[4]) | ((unsigned)f2bf(dq * fn[5]) << 16);
        wv.w = (unsigned)f2bf(dq * fn[6]) | ((unsigned)f2bf(dq * fn[7]) << 16);
        *(uint4*)(g_next + (size_t)node * OUT_F + sub * 8) = wv;
    } else if (slot == 1) {   // lanes 8..15: rmw out row (f32, 256B)
        float4* op = (float4*)(out + (size_t)node * OUT_F + sub * 8);
        float4 o0 = op[0], o1 = op[1];
        o0.x = fmaf(score, fn[0], o0.x);
        o0.y = fmaf(score, fn[1], o0.y);
        o0.z = fmaf(score, fn[2], o0.z);
        o0.w = fmaf(score, fn[3], o0.w);
        o1.x = fmaf(score, fn[4], o1.x);
        o1.y = fmaf(score, fn[5], o1.y);
        o1.z = fmaf(score, fn[6], o1.z);
        o1.w = fmaf(score, fn[7], o1.w);
        op[0] = o0;
        op[1] = o1;
    }
}

// ---------------------------------------------------------------------------
extern "C" void kernel_launch(void* const* d_in, const int* in_sizes, int n_in,
                              void* d_out, int out_size, void* d_ws, size_t ws_size,
                              hipStream_t stream) {
    const float* x  = (const float*)d_in[0];
    const void*  ei = d_in[1];
    const float* W1 = (const float*)d_in[2];
    const float* W2 = (const float*)d_in[3];
    const float* sv = (const float*)d_in[4];
    float* out = (float*)d_out;

    char* p = (char*)d_ws;
    auto alloc = [&](size_t bytes) -> char* {
        char* r = p;
        p += (bytes + 255) & ~(size_t)255;
        return r;
    };
    unsigned short* gA = (unsigned short*)alloc(sizeof(unsigned short) * N_NODES * OUT_F);
    unsigned short* gB = (unsigned short*)alloc(sizeof(unsigned short) * N_NODES * OUT_F);
    int*   src32     = (int*)alloc(sizeof(int) * N_EDGES);
    int*   dst32     = (int*)alloc(sizeof(int) * N_EDGES);
    // partials (16.8 MB) dead after hist_scan; entries_raw (12.8 MB) aliases it.
    char*  shared_region = alloc(sizeof(unsigned int) * 4 * HIST_BLOCKS * HIST_WORDS);
    unsigned int* partials = (unsigned int*)shared_region;
    int*   entries_raw = (int*)shared_region;
    int*   srcs      = (int*)alloc(sizeof(int) * N_EDGES);                      // 12.8 MB
    float* dinv_out  = (float*)alloc(sizeof(float) * N_NODES);
    float* dinv_in   = (float*)alloc(sizeof(float) * N_NODES);
    int*   row_start = (int*)alloc(sizeof(int) * (N_NODES + 1));
    int*   bucket_cnt   = (int*)alloc(sizeof(int) * NBKT);
    int*   bucket_start = (int*)alloc(sizeof(int) * (NBKT + 1));
    int*   gcur      = (int*)alloc(sizeof(int) * NBKT);
    int*   flag      = (int*)alloc(256);

    hipMemsetAsync(flag, 0, sizeof(int), stream);
    hipMemsetAsync(bucket_cnt, 0, sizeof(int) * NBKT, stream);

    detect_i32_kernel<<<4, 256, 0, stream>>>((const unsigned int*)ei, flag);
    convert_kernel<<<(N_EDGES / 2 + 255) / 256, 256, 0, stream>>>(ei, flag, src32, dst32);

    hist_kernel<<<dim3(HIST_BLOCKS, 4), 256, 0, stream>>>(src32, partials);
    hist_scan_kernel<<<(4 * HIST_WORDS + 255) / 256, 256, 0, stream>>>(partials, dinv_out);

    bucket_cnt_kernel<<<BKZ_BLOCKS, 256, 0, stream>>>(dst32, bucket_cnt);
    bucket_scan_kernel<<<1, 256, 0, stream>>>(bucket_cnt, bucket_start, gcur, row_start);
    bucketize_kernel<<<BKZ_BLOCKS, 256, 0, stream>>>(src32, dst32, gcur, entries_raw);

    hipFuncSetAttribute((const void*)sort_kernel,
                        hipFuncAttributeMaxDynamicSharedMemorySize, SORT_LDS_BYTES);
    sort_kernel<<<NBKT, 1024, SORT_LDS_BYTES, stream>>>(entries_raw, bucket_start,
                                                        srcs, row_start, dinv_in);

    int mlp_blocks = (N_NODES + 63) / 64;                   // 1563
    mlp_kernel<<<mlp_blocks, 256, 0, stream>>>(x, W1, W2, sv, dinv_out, out, gA);

    int node_blocks = (N_NODES + 3) / 4;                    // 25000
    unsigned short* cur = gA;
    unsigned short* nxt = gB;
    for (int hop = 0; hop < K_HOPS; ++hop) {
        hop_kernel<<<node_blocks, 256, 0, stream>>>(cur, row_start, srcs,
                                                    dinv_in, dinv_out, sv, nxt, out);
        unsigned short* t = cur; cur = nxt; nxt = t;
    }
}

// Round 11
// 827.468 us; speedup vs baseline: 2.7681x; 1.0166x over previous
//
#include <hip/hip_runtime.h>
#include <hip/hip_bf16.h>

#define N_NODES 100000
#define N_EDGES 3200000
#define IN_F 512
#define HID 64
#define OUT_F 64
#define K_HOPS 10

// src histogram geometry: 4 ranges of 32768 bins cover 131072 >= N_NODES
#define HIST_BLOCKS 64
#define HIST_BINS 32768
#define HIST_WORDS (HIST_BINS / 2)              // 16384 packed dual-uint16 words
#define EDGES_PER_HIST_BLOCK (N_EDGES / HIST_BLOCKS)  // 50000

// bucket geometry: 224 buckets x 448 nodes = 100352 >= N_NODES
#define NBKT 224
#define NBN  448
#define BKT_CAP 16384                            // mean 14286, sd ~120: safe
// bucketize pass
#define BKZ_BLOCKS 256
#define EDGES_PER_BKZ_BLOCK (N_EDGES / BKZ_BLOCKS)    // 12500
#define BKZ_BATCH 8192

typedef __attribute__((ext_vector_type(8))) short bf16x8;
typedef __attribute__((ext_vector_type(4))) float f32x4;

static __device__ __forceinline__ unsigned short f2bf(float f) {
    unsigned int u = __float_as_uint(f);
    u += 0x7FFFu + ((u >> 16) & 1u);            // round-to-nearest-even
    return (unsigned short)(u >> 16);
}
static __device__ __forceinline__ float bf2f(unsigned short s) {
    return __uint_as_float(((unsigned int)s) << 16);
}

// ---------------------------------------------------------------------------
__global__ void detect_i32_kernel(const unsigned int* ei_words, int* flag_is32) {
    int i = blockIdx.x * blockDim.x + threadIdx.x;  // 0..1023
    unsigned int w = ei_words[2 * i + 1];
    if (w != 0u) atomicOr(flag_is32, 1);
}

__global__ void __launch_bounds__(256) convert_kernel(const void* ei_raw, const int* flag_is32,
                                                      int* __restrict__ src32,
                                                      int* __restrict__ dst32) {
    int t = blockIdx.x * blockDim.x + threadIdx.x;     // 0 .. N_EDGES/2-1
    if (t >= N_EDGES / 2) return;
    if (*flag_is32) {
        const int2* ei = (const int2*)ei_raw;
        *(int2*)(src32 + 2 * t) = ei[t];
        *(int2*)(dst32 + 2 * t) = ei[N_EDGES / 2 + t];
    } else {
        const longlong2* ei = (const longlong2*)ei_raw;
        longlong2 s = ei[t];
        longlong2 d = ei[N_EDGES / 2 + t];
        *(int2*)(src32 + 2 * t) = make_int2((int)s.x, (int)s.y);
        *(int2*)(dst32 + 2 * t) = make_int2((int)d.x, (int)d.y);
    }
}

// Pre-swizzle W1/W2 into global B-fragment bf16 layout:
// bfrag[(((gt*4 + nt)*64) + (kgs*16 + cm))*8 + ko] = W[(gt*32+kgs*8+ko)*64 + nt*16+cm]
__global__ void __launch_bounds__(256) wconv_kernel(const float* __restrict__ W1,
                                                    const float* __restrict__ W2,
                                                    unsigned short* __restrict__ b1g,
                                                    unsigned short* __restrict__ b2g) {
    int o = blockIdx.x * blockDim.x + threadIdx.x;     // 0..36863
    int which = (o >= IN_F * HID);                      // 0: W1, 1: W2
    int oo = which ? (o - IN_F * HID) : o;
    int ko = oo & 7;
    int l = (oo >> 3) & 63;
    int kgs = l >> 4;
    int cm = l & 15;
    int tile = oo >> 9;
    int gt = tile >> 2;
    int nt = tile & 3;
    int k = gt * 32 + kgs * 8 + ko;
    int c = nt * 16 + cm;
    if (which) b2g[oo] = f2bf(W2[k * OUT_F + c]);
    else       b1g[oo] = f2bf(W1[k * HID + c]);
}

// Partial histograms of the src array in LDS (packed dual-uint16).
// grid = (HIST_BLOCKS slices, 4 ranges).
__global__ void __launch_bounds__(256) hist_kernel(const int* __restrict__ a,
                                                   unsigned int* __restrict__ partials) {
    __shared__ unsigned int cnt[HIST_WORDS];   // 64 KB
    int tid = threadIdx.x;
    for (int w = tid; w < HIST_WORDS; w += 256) cnt[w] = 0u;
    __syncthreads();

    int range = blockIdx.y;
    unsigned lo = (unsigned)(range * HIST_BINS);
    int beg = blockIdx.x * EDGES_PER_HIST_BLOCK;
    int end = beg + EDGES_PER_HIST_BLOCK;
    for (int i = beg + tid; i < end; i += 256) {
        unsigned v = (unsigned)a[i] - lo;
        if (v < HIST_BINS) atomicAdd(&cnt[v >> 1], 1u << ((v & 1u) * 16u));
    }
    __syncthreads();

    unsigned int* outp = partials + ((size_t)(blockIdx.y * HIST_BLOCKS + blockIdx.x)) * HIST_WORDS;
    for (int w = tid; w < HIST_WORDS / 4; w += 256)
        ((uint4*)outp)[w] = ((const uint4*)cnt)[w];
}

// Per-bin reduce over the 64 block-partials -> dinv_out.
__global__ void __launch_bounds__(256) hist_scan_kernel(const unsigned int* __restrict__ partials,
                                                        float* __restrict__ dinv) {
    int wg = blockIdx.x * blockDim.x + threadIdx.x;     // 0 .. 4*HIST_WORDS-1
    if (wg >= 4 * HIST_WORDS) return;
    int range = wg >> 14;
    int word = wg & (HIST_WORDS - 1);
    const unsigned int* base = partials + ((size_t)range * HIST_BLOCKS) * HIST_WORDS + word;
    unsigned lo = 0, hi = 0;
    for (int b = 0; b < HIST_BLOCKS; ++b) {
        unsigned c = base[(size_t)b * HIST_WORDS];
        lo += c & 0xffffu;
        hi += c >> 16;
    }
    int v0 = range * HIST_BINS + 2 * word;
    if (v0 < N_NODES) dinv[v0] = lo ? rsqrtf((float)lo) : 0.0f;
    int v1 = v0 + 1;
    if (v1 < N_NODES) dinv[v1] = hi ? rsqrtf((float)hi) : 0.0f;
}

// 224-bin per-bucket edge count (cheap; global atomics on only 224 bins).
__global__ void __launch_bounds__(256) bucket_cnt_kernel(const int* __restrict__ dst32,
                                                         int* __restrict__ bucket_cnt) {
    __shared__ int c[NBKT];
    int tid = threadIdx.x;
    if (tid < NBKT) c[tid] = 0;
    __syncthreads();
    int beg = blockIdx.x * EDGES_PER_BKZ_BLOCK;
    int end = beg + EDGES_PER_BKZ_BLOCK;
    for (int i = beg + tid; i < end; i += 256) {
        atomicAdd(&c[dst32[i] / NBN], 1);
    }
    __syncthreads();
    if (tid < NBKT && c[tid] > 0) atomicAdd(&bucket_cnt[tid], c[tid]);
}

// Scan bucket counts -> bucket_start[NBKT+1], gcur; also row_start[N]=E.
__global__ void __launch_bounds__(256) bucket_scan_kernel(const int* __restrict__ bucket_cnt,
                                                          int* __restrict__ bucket_start,
                                                          int* __restrict__ gcur,
                                                          int* __restrict__ row_start) {
    __shared__ int s[256];
    int t = threadIdx.x;
    int c = (t < NBKT) ? bucket_cnt[t] : 0;
    s[t] = c;
    __syncthreads();
    for (int off = 1; off < 256; off <<= 1) {
        int add = (t >= off) ? s[t - off] : 0;
        __syncthreads();
        s[t] += add;
        __syncthreads();
    }
    if (t < NBKT) {
        int excl = s[t] - c;
        bucket_start[t] = excl;
        gcur[t] = excl;
        if (t == NBKT - 1) {
            bucket_start[NBKT] = s[t];
            row_start[N_NODES] = s[t];
        }
    }
}

// Coarse bucketing with LDS-staged coalesced flushes. Entry = (src<<9)|dst_local.
__global__ void __launch_bounds__(256) bucketize_kernel(const int* __restrict__ src32,
                                                        const int* __restrict__ dst32,
                                                        int* __restrict__ gcur,
                                                        int* __restrict__ entries) {
    __shared__ unsigned int stag[BKZ_BATCH];     // 32 KB
    __shared__ unsigned char stagb[BKZ_BATCH];   // 8 KB
    __shared__ int cnt[256], sAr[256], ofs_l[256], gbase_l[256];

    int tid = threadIdx.x;
    int beg = blockIdx.x * EDGES_PER_BKZ_BLOCK;

    for (int bb = 0; bb < EDGES_PER_BKZ_BLOCK; bb += BKZ_BATCH) {
        int bn = min(BKZ_BATCH, EDGES_PER_BKZ_BLOCK - bb);
        cnt[tid] = 0;
        __syncthreads();

        unsigned pk[32];
#pragma unroll
        for (int j = 0; j < 32; ++j) {
            int loc = j * 256 + tid;
            pk[j] = 0xFFFFFFFFu;
            if (loc < bn) {
                int d = dst32[beg + bb + loc];
                int b = d / NBN;
                int dl = d - b * NBN;
                int off = atomicAdd(&cnt[b], 1);
                pk[j] = ((unsigned)b << 22) | ((unsigned)dl << 13) | (unsigned)off;
            }
        }
        __syncthreads();
        int c = cnt[tid];
        sAr[tid] = c;
        __syncthreads();
        for (int off = 1; off < 256; off <<= 1) {
            int add = (tid >= off) ? sAr[tid - off] : 0;
            __syncthreads();
            sAr[tid] += add;
            __syncthreads();
        }
        ofs_l[tid] = sAr[tid] - c;
        if (tid < NBKT && c > 0) gbase_l[tid] = atomicAdd(&gcur[tid], c);
        __syncthreads();

#pragma unroll
        for (int j = 0; j < 32; ++j) {
            int loc = j * 256 + tid;
            if (loc < bn && pk[j] != 0xFFFFFFFFu) {
                int s = src32[beg + bb + loc];
                int b = pk[j] >> 22;
                int dl = (pk[j] >> 13) & 511;
                int off = pk[j] & 8191;
                int pos = ofs_l[b] + off;
                stag[pos] = ((unsigned)s << 9) | (unsigned)dl;
                stagb[pos] = (unsigned char)b;
            }
        }
        __syncthreads();
        for (int i = tid; i < bn; i += 256) {
            int b = stagb[i];
            entries[gbase_l[b] + (i - ofs_l[b])] = (int)stag[i];
        }
        __syncthreads();
    }
}

// Per-bucket counting sort in LDS: produces dst-sorted src-only CSR and
// writes row_start + dinv_in for its 448 nodes (no global scan needed).
#define SORT_LDS_BYTES ((2 * BKT_CAP + 512 + 512) * 4)    // 135,168 B
__global__ void __launch_bounds__(1024) sort_kernel(const int* __restrict__ entries,
                                                    const int* __restrict__ bucket_start,
                                                    int* __restrict__ srcs,
                                                    int* __restrict__ row_start,
                                                    float* __restrict__ dinv_in) {
    extern __shared__ int sbuf[];
    int* sin  = sbuf;                    // BKT_CAP
    int* sout = sbuf + BKT_CAP;          // BKT_CAP
    int* cnt  = sbuf + 2 * BKT_CAP;      // 512
    int* nsum = cnt + 512;               // 512
    int tid = threadIdx.x;
    int b = blockIdx.x;
    int ebeg = bucket_start[b];
    int eend = bucket_start[b + 1];
    int n = eend - ebeg;

    for (int i = tid; i < n; i += 1024) sin[i] = entries[ebeg + i];
    if (tid < 512) { cnt[tid] = 0; nsum[tid] = 0; }
    __syncthreads();
    for (int i = tid; i < n; i += 1024) {
        atomicAdd(&cnt[(unsigned)sin[i] & 511u], 1);
    }
    __syncthreads();
    int c = (tid < 512) ? cnt[tid] : 0;
    if (tid < 512) nsum[tid] = c;
    __syncthreads();
    for (int off = 1; off < 512; off <<= 1) {     // Hillis-Steele inclusive
        int v = (tid < 512 && tid >= off) ? nsum[tid - off] : 0;
        __syncthreads();
        if (tid < 512) nsum[tid] += v;
        __syncthreads();
    }
    if (tid < NBN) {
        int excl = nsum[tid] - c;
        cnt[tid] = excl;                          // reuse as cursor
        int node = b * NBN + tid;
        if (node < N_NODES) {
            row_start[node] = ebeg + excl;
            dinv_in[node] = c ? rsqrtf((float)c) : 0.0f;
        }
    }
    __syncthreads();
    for (int i = tid; i < n; i += 1024) {
        unsigned e = (unsigned)sin[i];
        int pos = atomicAdd(&cnt[e & 511u], 1);
        sout[pos] = (int)(e >> 9);
    }
    __syncthreads();
    for (int i = tid; i < n; i += 1024) srcs[ebeg + i] = sout[i];
}

// ---------------------------------------------------------------------------
// MFMA MLP + fused initial combine + g0 = dinv_out * h (bf16).
// B-fragments pre-swizzled in GLOBAL (b1g/b2g, L2-broadcast-hot across all
// blocks) -- no LDS weight staging, no staging barriers, 8 KB LDS total.
__global__ void __launch_bounds__(256) mlp_kernel(const float* __restrict__ x,
                                                  const unsigned short* __restrict__ b1g,
                                                  const unsigned short* __restrict__ b2g,
                                                  const float* __restrict__ sv,
                                                  const float* __restrict__ dinv_out,
                                                  float* __restrict__ out,
                                                  unsigned short* __restrict__ g0) {
    __shared__ __align__(16) unsigned short a2s[4][2 * 64 * 8];   // 8 KB per-wave layer2 A

    int tid = threadIdx.x;
    int w = tid >> 6;
    int l = tid & 63;
    int kg = l >> 4;
    int m  = l & 15;
    int row0 = blockIdx.x * 64;
    int row = row0 + w * 16 + m;
    bool valid = row < N_NODES;
    const float* xp = x + (size_t)row * IN_F + kg * 8;

    f32x4 acc[4];
#pragma unroll
    for (int nt = 0; nt < 4; ++nt) acc[nt] = (f32x4){0.f, 0.f, 0.f, 0.f};

#pragma unroll 4
    for (int gt = 0; gt < 16; ++gt) {
        union { bf16x8 v; unsigned short u[8]; } a;
        if (valid) {
            const float* ap = xp + gt * 32;
            float4 u0 = *(const float4*)ap;
            float4 u1 = *(const float4*)(ap + 4);
            a.u[0] = f2bf(u0.x); a.u[1] = f2bf(u0.y);
            a.u[2] = f2bf(u0.z); a.u[3] = f2bf(u0.w);
            a.u[4] = f2bf(u1.x); a.u[5] = f2bf(u1.y);
            a.u[6] = f2bf(u1.z); a.u[7] = f2bf(u1.w);
        } else {
#pragma unroll
            for (int q = 0; q < 8; ++q) a.u[q] = 0;
        }
#pragma unroll
        for (int nt = 0; nt < 4; ++nt) {
            bf16x8 b = *(const bf16x8*)&b1g[((gt * 4 + nt) * 64 + l) * 8];
            acc[nt] = __builtin_amdgcn_mfma_f32_16x16x32_bf16(a.v, b, acc[nt], 0, 0, 0);
        }
    }

    // relu(h1) -> bf16 -> per-wave LDS restage into layer-2 A-frag layout
#pragma unroll
    for (int nt = 0; nt < 4; ++nt) {
#pragma unroll
        for (int reg = 0; reg < 4; ++reg) {
            float v = fmaxf(acc[nt][reg], 0.0f);
            int cc = nt * 16 + m;
            int r = kg * 4 + reg;
            a2s[w][((cc >> 5) * 64 + (((cc >> 3) & 3) * 16 + r)) * 8 + (cc & 7)] = f2bf(v);
        }
    }

    f32x4 acc2[4];
#pragma unroll
    for (int nt = 0; nt < 4; ++nt) acc2[nt] = (f32x4){0.f, 0.f, 0.f, 0.f};
#pragma unroll
    for (int t2 = 0; t2 < 2; ++t2) {
        bf16x8 a = *(const bf16x8*)&a2s[w][(t2 * 64 + l) * 8];
#pragma unroll
        for (int nt = 0; nt < 4; ++nt) {
            bf16x8 b = *(const bf16x8*)&b2g[((t2 * 4 + nt) * 64 + l) * 8];
            acc2[nt] = __builtin_amdgcn_mfma_f32_16x16x32_bf16(a, b, acc2[nt], 0, 0, 0);
        }
    }

    // fused epilogue: relu, gate, out init, g0
    float vals[4][4];
    float pr[4] = {0.f, 0.f, 0.f, 0.f};
#pragma unroll
    for (int nt = 0; nt < 4; ++nt) {
        float s_c = sv[nt * 16 + m];
#pragma unroll
        for (int reg = 0; reg < 4; ++reg) {
            float v = fmaxf(acc2[nt][reg], 0.0f);
            vals[nt][reg] = v;
            pr[reg] = fmaf(v, s_c, pr[reg]);
        }
    }
#pragma unroll
    for (int off = 1; off <= 8; off <<= 1) {
#pragma unroll
        for (int reg = 0; reg < 4; ++reg) pr[reg] += __shfl_xor(pr[reg], off, 64);
    }
#pragma unroll
    for (int reg = 0; reg < 4; ++reg) {
        int node = row0 + w * 16 + kg * 4 + reg;
        if (node < N_NODES) {
            float score = 1.0f / (1.0f + expf(-pr[reg]));
            float dv = dinv_out[node];
#pragma unroll
            for (int nt = 0; nt < 4; ++nt) {
                out[(size_t)node * OUT_F + nt * 16 + m] = score * vals[nt][reg];
                g0[(size_t)node * OUT_F + nt * 16 + m] = f2bf(dv * vals[nt][reg]);
            }
        }
    }
}

// ---------------------------------------------------------------------------
// One hop + fused gate-combine (round-8 structure, measured ~60us/hop).
// One wave per dst node; src-only sorted CSR; 8 independent gathers in flight.
// g carries dinv_out-folded features: S = sum g[src]; fn = dinv_in*S;
// out += sigmoid(fn.s)*fn; g_next = dinv_out*fn.
__global__ void __launch_bounds__(256) hop_kernel(
        const unsigned short* __restrict__ g_prev,
        const int* __restrict__ row_start,
        const int* __restrict__ srcs,
        const float* __restrict__ dinv_in,
        const float* __restrict__ dinv_out,
        const float* __restrict__ sv,
        unsigned short* __restrict__ g_next,
        float* __restrict__ out) {
    int lane = threadIdx.x & 63;
    int node = blockIdx.x * 4 + (threadIdx.x >> 6);
    if (node >= N_NODES) return;
    int beg = row_start[node];
    int end = row_start[node + 1];
    int slot = lane >> 3;    // 0..7: edge slot
    int sub  = lane & 7;     // feature group: features 8*sub..8*sub+7

    float acc[8];
#pragma unroll
    for (int j = 0; j < 8; ++j) acc[j] = 0.0f;

    for (int chunk = beg; chunk < end; chunk += 64) {
        int nrem = end - chunk;                       // wave-uniform
        int es = (chunk + lane < end) ? srcs[chunk + lane] : 0;  // coalesced 256B

        uint4 v[8];
#pragma unroll
        for (int g = 0; g < 8; ++g) {
            int s = __shfl(es, g * 8 + slot, 64);
            if (g * 8 + slot < nrem)
                v[g] = *(const uint4*)(g_prev + (size_t)s * OUT_F + sub * 8);
        }
#pragma unroll
        for (int g = 0; g < 8; ++g) {
            if (g * 8 + slot < nrem) {
                acc[0] += __uint_as_float(v[g].x << 16);
                acc[1] += __uint_as_float(v[g].x & 0xffff0000u);
                acc[2] += __uint_as_float(v[g].y << 16);
                acc[3] += __uint_as_float(v[g].y & 0xffff0000u);
                acc[4] += __uint_as_float(v[g].z << 16);
                acc[5] += __uint_as_float(v[g].z & 0xffff0000u);
                acc[6] += __uint_as_float(v[g].w << 16);
                acc[7] += __uint_as_float(v[g].w & 0xffff0000u);
            }
        }
    }
#pragma unroll
    for (int off = 8; off <= 32; off <<= 1) {
#pragma unroll
        for (int j = 0; j < 8; ++j) acc[j] += __shfl_xor(acc[j], off, 64);
    }
    float di = dinv_in[node];
    float dq = dinv_out[node];
    float fn[8];
#pragma unroll
    for (int j = 0; j < 8; ++j) fn[j] = di * acc[j];

    float4 s0 = *(const float4*)(sv + sub * 8);
    float4 s1 = *(const float4*)(sv + sub * 8 + 4);
    float p = fn[0] * s0.x + fn[1] * s0.y + fn[2] * s0.z + fn[3] * s0.w
            + fn[4] * s1.x + fn[5] * s1.y + fn[6] * s1.z + fn[7] * s1.w;
#pragma unroll
    for (int off = 1; off <= 4; off <<= 1) p += __shfl_xor(p, off, 64);
    float score = 1.0f / (1.0f + expf(-p));

    if (slot == 0) {          // lanes 0..7: write g_next row (bf16, 128B)
        uint4 wv;
        wv.x = (unsigned)f2bf(dq * fn[0]) | ((unsigned)f2bf(dq * fn[1]) << 16);
        wv.y = (unsigned)f2bf(dq * fn[2]) | ((unsigned)f2bf(dq * fn[3]) << 16);
        wv.z = (unsigned)f2bf(dq * fn[4]) | ((unsigned)f2bf(dq * fn[5]) << 16);
        wv.w = (unsigned)f2bf(dq * fn[6]) | ((unsigned)f2bf(dq * fn[7]) << 16);
        *(uint4*)(g_next + (size_t)node * OUT_F + sub * 8) = wv;
    } else if (slot == 1) {   // lanes 8..15: rmw out row (f32, 256B)
        float4* op = (float4*)(out + (size_t)node * OUT_F + sub * 8);
        float4 o0 = op[0], o1 = op[1];
        o0.x = fmaf(score, fn[0], o0.x);
        o0.y = fmaf(score, fn[1], o0.y);
        o0.z = fmaf(score, fn[2], o0.z);
        o0.w = fmaf(score, fn[3], o0.w);
        o1.x = fmaf(score, fn[4], o1.x);
        o1.y = fmaf(score, fn[5], o1.y);
        o1.z = fmaf(score, fn[6], o1.z);
        o1.w = fmaf(score, fn[7], o1.w);
        op[0] = o0;
        op[1] = o1;
    }
}

// ---------------------------------------------------------------------------
extern "C" void kernel_launch(void* const* d_in, const int* in_sizes, int n_in,
                              void* d_out, int out_size, void* d_ws, size_t ws_size,
                              hipStream_t stream) {
    const float* x  = (const float*)d_in[0];
    const void*  ei = d_in[1];
    const float* W1 = (const float*)d_in[2];
    const float* W2 = (const float*)d_in[3];
    const float* sv = (const float*)d_in[4];
    float* out = (float*)d_out;

    char* p = (char*)d_ws;
    auto alloc = [&](size_t bytes) -> char* {
        char* r = p;
        p += (bytes + 255) & ~(size_t)255;
        return r;
    };
    unsigned short* gA = (unsigned short*)alloc(sizeof(unsigned short) * N_NODES * OUT_F);
    unsigned short* gB = (unsigned short*)alloc(sizeof(unsigned short) * N_NODES * OUT_F);
    int*   src32     = (int*)alloc(sizeof(int) * N_EDGES);
    int*   dst32     = (int*)alloc(sizeof(int) * N_EDGES);
    // partials (16.8 MB) dead after hist_scan; entries_raw (12.8 MB) aliases it.
    char*  shared_region = alloc(sizeof(unsigned int) * 4 * HIST_BLOCKS * HIST_WORDS);
    unsigned int* partials = (unsigned int*)shared_region;
    int*   entries_raw = (int*)shared_region;
    int*   srcs      = (int*)alloc(sizeof(int) * N_EDGES);                      // 12.8 MB
    unsigned short* b1g = (unsigned short*)alloc(sizeof(unsigned short) * IN_F * HID);
    unsigned short* b2g = (unsigned short*)alloc(sizeof(unsigned short) * HID * OUT_F);
    float* dinv_out  = (float*)alloc(sizeof(float) * N_NODES);
    float* dinv_in   = (float*)alloc(sizeof(float) * N_NODES);
    int*   row_start = (int*)alloc(sizeof(int) * (N_NODES + 1));
    int*   bucket_cnt   = (int*)alloc(sizeof(int) * NBKT);
    int*   bucket_start = (int*)alloc(sizeof(int) * (NBKT + 1));
    int*   gcur      = (int*)alloc(sizeof(int) * NBKT);
    int*   flag      = (int*)alloc(256);

    hipMemsetAsync(flag, 0, sizeof(int), stream);
    hipMemsetAsync(bucket_cnt, 0, sizeof(int) * NBKT, stream);

    detect_i32_kernel<<<4, 256, 0, stream>>>((const unsigned int*)ei, flag);
    convert_kernel<<<(N_EDGES / 2 + 255) / 256, 256, 0, stream>>>(ei, flag, src32, dst32);
    wconv_kernel<<<(IN_F * HID + HID * OUT_F + 255) / 256, 256, 0, stream>>>(W1, W2, b1g, b2g);

    hist_kernel<<<dim3(HIST_BLOCKS, 4), 256, 0, stream>>>(src32, partials);
    hist_scan_kernel<<<(4 * HIST_WORDS + 255) / 256, 256, 0, stream>>>(partials, dinv_out);

    bucket_cnt_kernel<<<BKZ_BLOCKS, 256, 0, stream>>>(dst32, bucket_cnt);
    bucket_scan_kernel<<<1, 256, 0, stream>>>(bucket_cnt, bucket_start, gcur, row_start);
    bucketize_kernel<<<BKZ_BLOCKS, 256, 0, stream>>>(src32, dst32, gcur, entries_raw);

    hipFuncSetAttribute((const void*)sort_kernel,
                        hipFuncAttributeMaxDynamicSharedMemorySize, SORT_LDS_BYTES);
    sort_kernel<<<NBKT, 1024, SORT_LDS_BYTES, stream>>>(entries_raw, bucket_start,
                                                        srcs, row_start, dinv_in);

    int mlp_blocks = (N_NODES + 63) / 64;                   // 1563
    mlp_kernel<<<mlp_blocks, 256, 0, stream>>>(x, b1g, b2g, sv, dinv_out, out, gA);

    int node_blocks = (N_NODES + 3) / 4;                    // 25000
    unsigned short* cur = gA;
    unsigned short* nxt = gB;
    for (int hop = 0; hop < K_HOPS; ++hop) {
        hop_kernel<<<node_blocks, 256, 0, stream>>>(cur, row_start, srcs,
                                                    dinv_in, dinv_out, sv, nxt, out);
        unsigned short* t = cur; cur = nxt; nxt = t;
    }
}

// Round 12
// 799.866 us; speedup vs baseline: 2.8636x; 1.0345x over previous
//
#include <hip/hip_runtime.h>
#include <hip/hip_bf16.h>

#define N_NODES 100000
#define N_EDGES 3200000
#define IN_F 512
#define HID 64
#define OUT_F 64
#define K_HOPS 10

// src histogram geometry: 4 ranges of 32768 bins cover 131072 >= N_NODES
#define HIST_BLOCKS 64
#define HIST_BINS 32768
#define HIST_WORDS (HIST_BINS / 2)              // 16384 packed dual-uint16 words
#define EDGES_PER_HIST_BLOCK (N_EDGES / HIST_BLOCKS)  // 50000

// bucket geometry: 224 buckets x 448 nodes = 100352 >= N_NODES
#define NBKT 224
#define NBN  448
#define BKT_CAP 16384                            // mean 14286, sd ~120: safe
// bucketize pass
#define BKZ_BLOCKS 256
#define EDGES_PER_BKZ_BLOCK (N_EDGES / BKZ_BLOCKS)    // 12500
#define BKZ_BATCH 8192

typedef __attribute__((ext_vector_type(8))) short bf16x8;
typedef __attribute__((ext_vector_type(4))) float f32x4;

static __device__ __forceinline__ unsigned short f2bf(float f) {
    unsigned int u = __float_as_uint(f);
    u += 0x7FFFu + ((u >> 16) & 1u);            // round-to-nearest-even
    return (unsigned short)(u >> 16);
}
static __device__ __forceinline__ float bf2f(unsigned short s) {
    return __uint_as_float(((unsigned int)s) << 16);
}

// ---------------------------------------------------------------------------
__global__ void detect_i32_kernel(const unsigned int* ei_words, int* flag_is32) {
    int i = blockIdx.x * blockDim.x + threadIdx.x;  // 0..1023
    unsigned int w = ei_words[2 * i + 1];
    if (w != 0u) atomicOr(flag_is32, 1);
}

__global__ void __launch_bounds__(256) convert_kernel(const void* ei_raw, const int* flag_is32,
                                                      int* __restrict__ src32,
                                                      int* __restrict__ dst32) {
    int t = blockIdx.x * blockDim.x + threadIdx.x;     // 0 .. N_EDGES/2-1
    if (t >= N_EDGES / 2) return;
    if (*flag_is32) {
        const int2* ei = (const int2*)ei_raw;
        *(int2*)(src32 + 2 * t) = ei[t];
        *(int2*)(dst32 + 2 * t) = ei[N_EDGES / 2 + t];
    } else {
        const longlong2* ei = (const longlong2*)ei_raw;
        longlong2 s = ei[t];
        longlong2 d = ei[N_EDGES / 2 + t];
        *(int2*)(src32 + 2 * t) = make_int2((int)s.x, (int)s.y);
        *(int2*)(dst32 + 2 * t) = make_int2((int)d.x, (int)d.y);
    }
}

// Pre-swizzle W1/W2 into global B-fragment bf16 layout.
__global__ void __launch_bounds__(256) wconv_kernel(const float* __restrict__ W1,
                                                    const float* __restrict__ W2,
                                                    unsigned short* __restrict__ b1g,
                                                    unsigned short* __restrict__ b2g) {
    int o = blockIdx.x * blockDim.x + threadIdx.x;     // 0..36863
    int which = (o >= IN_F * HID);                      // 0: W1, 1: W2
    int oo = which ? (o - IN_F * HID) : o;
    int ko = oo & 7;
    int l = (oo >> 3) & 63;
    int kgs = l >> 4;
    int cm = l & 15;
    int tile = oo >> 9;
    int gt = tile >> 2;
    int nt = tile & 3;
    int k = gt * 32 + kgs * 8 + ko;
    int c = nt * 16 + cm;
    if (which) b2g[oo] = f2bf(W2[k * OUT_F + c]);
    else       b1g[oo] = f2bf(W1[k * HID + c]);
}

// Partial histograms of the src array in LDS (packed dual-uint16).
__global__ void __launch_bounds__(256) hist_kernel(const int* __restrict__ a,
                                                   unsigned int* __restrict__ partials) {
    __shared__ unsigned int cnt[HIST_WORDS];   // 64 KB
    int tid = threadIdx.x;
    for (int w = tid; w < HIST_WORDS; w += 256) cnt[w] = 0u;
    __syncthreads();

    int range = blockIdx.y;
    unsigned lo = (unsigned)(range * HIST_BINS);
    int beg = blockIdx.x * EDGES_PER_HIST_BLOCK;
    int end = beg + EDGES_PER_HIST_BLOCK;
    for (int i = beg + tid; i < end; i += 256) {
        unsigned v = (unsigned)a[i] - lo;
        if (v < HIST_BINS) atomicAdd(&cnt[v >> 1], 1u << ((v & 1u) * 16u));
    }
    __syncthreads();

    unsigned int* outp = partials + ((size_t)(blockIdx.y * HIST_BLOCKS + blockIdx.x)) * HIST_WORDS;
    for (int w = tid; w < HIST_WORDS / 4; w += 256)
        ((uint4*)outp)[w] = ((const uint4*)cnt)[w];
}

// Per-bin reduce over the 64 block-partials -> dinv_out.
__global__ void __launch_bounds__(256) hist_scan_kernel(const unsigned int* __restrict__ partials,
                                                        float* __restrict__ dinv) {
    int wg = blockIdx.x * blockDim.x + threadIdx.x;     // 0 .. 4*HIST_WORDS-1
    if (wg >= 4 * HIST_WORDS) return;
    int range = wg >> 14;
    int word = wg & (HIST_WORDS - 1);
    const unsigned int* base = partials + ((size_t)range * HIST_BLOCKS) * HIST_WORDS + word;
    unsigned lo = 0, hi = 0;
    for (int b = 0; b < HIST_BLOCKS; ++b) {
        unsigned c = base[(size_t)b * HIST_WORDS];
        lo += c & 0xffffu;
        hi += c >> 16;
    }
    int v0 = range * HIST_BINS + 2 * word;
    if (v0 < N_NODES) dinv[v0] = lo ? rsqrtf((float)lo) : 0.0f;
    int v1 = v0 + 1;
    if (v1 < N_NODES) dinv[v1] = hi ? rsqrtf((float)hi) : 0.0f;
}

// 224-bin per-bucket edge count.
__global__ void __launch_bounds__(256) bucket_cnt_kernel(const int* __restrict__ dst32,
                                                         int* __restrict__ bucket_cnt) {
    __shared__ int c[NBKT];
    int tid = threadIdx.x;
    if (tid < NBKT) c[tid] = 0;
    __syncthreads();
    int beg = blockIdx.x * EDGES_PER_BKZ_BLOCK;
    int end = beg + EDGES_PER_BKZ_BLOCK;
    for (int i = beg + tid; i < end; i += 256) {
        atomicAdd(&c[dst32[i] / NBN], 1);
    }
    __syncthreads();
    if (tid < NBKT && c[tid] > 0) atomicAdd(&bucket_cnt[tid], c[tid]);
}

// Scan bucket counts -> bucket_start[NBKT+1], gcur; also row_start[N]=E.
__global__ void __launch_bounds__(256) bucket_scan_kernel(const int* __restrict__ bucket_cnt,
                                                          int* __restrict__ bucket_start,
                                                          int* __restrict__ gcur,
                                                          int* __restrict__ row_start) {
    __shared__ int s[256];
    int t = threadIdx.x;
    int c = (t < NBKT) ? bucket_cnt[t] : 0;
    s[t] = c;
    __syncthreads();
    for (int off = 1; off < 256; off <<= 1) {
        int add = (t >= off) ? s[t - off] : 0;
        __syncthreads();
        s[t] += add;
        __syncthreads();
    }
    if (t < NBKT) {
        int excl = s[t] - c;
        bucket_start[t] = excl;
        gcur[t] = excl;
        if (t == NBKT - 1) {
            bucket_start[NBKT] = s[t];
            row_start[N_NODES] = s[t];
        }
    }
}

// Coarse bucketing with LDS-staged coalesced flushes. Entry = (src<<9)|dst_local.
__global__ void __launch_bounds__(256) bucketize_kernel(const int* __restrict__ src32,
                                                        const int* __restrict__ dst32,
                                                        int* __restrict__ gcur,
                                                        int* __restrict__ entries) {
    __shared__ unsigned int stag[BKZ_BATCH];     // 32 KB
    __shared__ unsigned char stagb[BKZ_BATCH];   // 8 KB
    __shared__ int cnt[256], sAr[256], ofs_l[256], gbase_l[256];

    int tid = threadIdx.x;
    int beg = blockIdx.x * EDGES_PER_BKZ_BLOCK;

    for (int bb = 0; bb < EDGES_PER_BKZ_BLOCK; bb += BKZ_BATCH) {
        int bn = min(BKZ_BATCH, EDGES_PER_BKZ_BLOCK - bb);
        cnt[tid] = 0;
        __syncthreads();

        unsigned pk[32];
#pragma unroll
        for (int j = 0; j < 32; ++j) {
            int loc = j * 256 + tid;
            pk[j] = 0xFFFFFFFFu;
            if (loc < bn) {
                int d = dst32[beg + bb + loc];
                int b = d / NBN;
                int dl = d - b * NBN;
                int off = atomicAdd(&cnt[b], 1);
                pk[j] = ((unsigned)b << 22) | ((unsigned)dl << 13) | (unsigned)off;
            }
        }
        __syncthreads();
        int c = cnt[tid];
        sAr[tid] = c;
        __syncthreads();
        for (int off = 1; off < 256; off <<= 1) {
            int add = (tid >= off) ? sAr[tid - off] : 0;
            __syncthreads();
            sAr[tid] += add;
            __syncthreads();
        }
        ofs_l[tid] = sAr[tid] - c;
        if (tid < NBKT && c > 0) gbase_l[tid] = atomicAdd(&gcur[tid], c);
        __syncthreads();

#pragma unroll
        for (int j = 0; j < 32; ++j) {
            int loc = j * 256 + tid;
            if (loc < bn && pk[j] != 0xFFFFFFFFu) {
                int s = src32[beg + bb + loc];
                int b = pk[j] >> 22;
                int dl = (pk[j] >> 13) & 511;
                int off = pk[j] & 8191;
                int pos = ofs_l[b] + off;
                stag[pos] = ((unsigned)s << 9) | (unsigned)dl;
                stagb[pos] = (unsigned char)b;
            }
        }
        __syncthreads();
        for (int i = tid; i < bn; i += 256) {
            int b = stagb[i];
            entries[gbase_l[b] + (i - ofs_l[b])] = (int)stag[i];
        }
        __syncthreads();
    }
}

// Per-bucket counting sort in LDS: produces dst-sorted src-only CSR and
// writes row_start + dinv_in for its 448 nodes.
#define SORT_LDS_BYTES ((2 * BKT_CAP + 512 + 512) * 4)    // 135,168 B
__global__ void __launch_bounds__(1024) sort_kernel(const int* __restrict__ entries,
                                                    const int* __restrict__ bucket_start,
                                                    int* __restrict__ srcs,
                                                    int* __restrict__ row_start,
                                                    float* __restrict__ dinv_in) {
    extern __shared__ int sbuf[];
    int* sin  = sbuf;                    // BKT_CAP
    int* sout = sbuf + BKT_CAP;          // BKT_CAP
    int* cnt  = sbuf + 2 * BKT_CAP;      // 512
    int* nsum = cnt + 512;               // 512
    int tid = threadIdx.x;
    int b = blockIdx.x;
    int ebeg = bucket_start[b];
    int eend = bucket_start[b + 1];
    int n = eend - ebeg;

    for (int i = tid; i < n; i += 1024) sin[i] = entries[ebeg + i];
    if (tid < 512) { cnt[tid] = 0; nsum[tid] = 0; }
    __syncthreads();
    for (int i = tid; i < n; i += 1024) {
        atomicAdd(&cnt[(unsigned)sin[i] & 511u], 1);
    }
    __syncthreads();
    int c = (tid < 512) ? cnt[tid] : 0;
    if (tid < 512) nsum[tid] = c;
    __syncthreads();
    for (int off = 1; off < 512; off <<= 1) {     // Hillis-Steele inclusive
        int v = (tid < 512 && tid >= off) ? nsum[tid - off] : 0;
        __syncthreads();
        if (tid < 512) nsum[tid] += v;
        __syncthreads();
    }
    if (tid < NBN) {
        int excl = nsum[tid] - c;
        cnt[tid] = excl;                          // reuse as cursor
        int node = b * NBN + tid;
        if (node < N_NODES) {
            row_start[node] = ebeg + excl;
            dinv_in[node] = c ? rsqrtf((float)c) : 0.0f;
        }
    }
    __syncthreads();
    for (int i = tid; i < n; i += 1024) {
        unsigned e = (unsigned)sin[i];
        int pos = atomicAdd(&cnt[e & 511u], 1);
        sout[pos] = (int)(e >> 9);
    }
    __syncthreads();
    for (int i = tid; i < n; i += 1024) srcs[ebeg + i] = sout[i];
}

// ---------------------------------------------------------------------------
// MFMA MLP: writes g0 = dinv_out * relu(relu(x@W1)@W2) in bf16 only.
// B-fragments pre-swizzled in GLOBAL (L2-broadcast-hot); 8 KB LDS total.
__global__ void __launch_bounds__(256) mlp_kernel(const float* __restrict__ x,
                                                  const unsigned short* __restrict__ b1g,
                                                  const unsigned short* __restrict__ b2g,
                                                  const float* __restrict__ dinv_out,
                                                  unsigned short* __restrict__ g0) {
    __shared__ __align__(16) unsigned short a2s[4][2 * 64 * 8];   // 8 KB per-wave layer2 A

    int tid = threadIdx.x;
    int w = tid >> 6;
    int l = tid & 63;
    int kg = l >> 4;
    int m  = l & 15;
    int row0 = blockIdx.x * 64;
    int row = row0 + w * 16 + m;
    bool valid = row < N_NODES;
    const float* xp = x + (size_t)row * IN_F + kg * 8;

    f32x4 acc[4];
#pragma unroll
    for (int nt = 0; nt < 4; ++nt) acc[nt] = (f32x4){0.f, 0.f, 0.f, 0.f};

#pragma unroll 4
    for (int gt = 0; gt < 16; ++gt) {
        union { bf16x8 v; unsigned short u[8]; } a;
        if (valid) {
            const float* ap = xp + gt * 32;
            float4 u0 = *(const float4*)ap;
            float4 u1 = *(const float4*)(ap + 4);
            a.u[0] = f2bf(u0.x); a.u[1] = f2bf(u0.y);
            a.u[2] = f2bf(u0.z); a.u[3] = f2bf(u0.w);
            a.u[4] = f2bf(u1.x); a.u[5] = f2bf(u1.y);
            a.u[6] = f2bf(u1.z); a.u[7] = f2bf(u1.w);
        } else {
#pragma unroll
            for (int q = 0; q < 8; ++q) a.u[q] = 0;
        }
#pragma unroll
        for (int nt = 0; nt < 4; ++nt) {
            bf16x8 b = *(const bf16x8*)&b1g[((gt * 4 + nt) * 64 + l) * 8];
            acc[nt] = __builtin_amdgcn_mfma_f32_16x16x32_bf16(a.v, b, acc[nt], 0, 0, 0);
        }
    }

    // relu(h1) -> bf16 -> per-wave LDS restage into layer-2 A-frag layout
#pragma unroll
    for (int nt = 0; nt < 4; ++nt) {
#pragma unroll
        for (int reg = 0; reg < 4; ++reg) {
            float v = fmaxf(acc[nt][reg], 0.0f);
            int cc = nt * 16 + m;
            int r = kg * 4 + reg;
            a2s[w][((cc >> 5) * 64 + (((cc >> 3) & 3) * 16 + r)) * 8 + (cc & 7)] = f2bf(v);
        }
    }

    f32x4 acc2[4];
#pragma unroll
    for (int nt = 0; nt < 4; ++nt) acc2[nt] = (f32x4){0.f, 0.f, 0.f, 0.f};
#pragma unroll
    for (int t2 = 0; t2 < 2; ++t2) {
        bf16x8 a = *(const bf16x8*)&a2s[w][(t2 * 64 + l) * 8];
#pragma unroll
        for (int nt = 0; nt < 4; ++nt) {
            bf16x8 b = *(const bf16x8*)&b2g[((t2 * 4 + nt) * 64 + l) * 8];
            acc2[nt] = __builtin_amdgcn_mfma_f32_16x16x32_bf16(a, b, acc2[nt], 0, 0, 0);
        }
    }

#pragma unroll
    for (int reg = 0; reg < 4; ++reg) {
        int node = row0 + w * 16 + kg * 4 + reg;
        if (node < N_NODES) {
            float dv = dinv_out[node];
#pragma unroll
            for (int nt = 0; nt < 4; ++nt) {
                g0[(size_t)node * OUT_F + nt * 16 + m] =
                    f2bf(dv * fmaxf(acc2[nt][reg], 0.0f));
            }
        }
    }
}

// ---------------------------------------------------------------------------
// One hop, pure propagation: g_next = (dinv_in*dinv_out)[dst] * sum g_prev[src].
// One wave per dst node; src-only sorted CSR; 8 independent gathers in flight.
__global__ void __launch_bounds__(256) hop_kernel(
        const unsigned short* __restrict__ g_prev,
        const int* __restrict__ row_start,
        const int* __restrict__ srcs,
        const float* __restrict__ dinv_in,
        const float* __restrict__ dinv_out,
        unsigned short* __restrict__ g_next) {
    int lane = threadIdx.x & 63;
    int node = blockIdx.x * 4 + (threadIdx.x >> 6);
    if (node >= N_NODES) return;
    int beg = row_start[node];
    int end = row_start[node + 1];
    int slot = lane >> 3;    // 0..7: edge slot
    int sub  = lane & 7;     // feature group: features 8*sub..8*sub+7

    float acc[8];
#pragma unroll
    for (int j = 0; j < 8; ++j) acc[j] = 0.0f;

    for (int chunk = beg; chunk < end; chunk += 64) {
        int nrem = end - chunk;                       // wave-uniform
        int es = (chunk + lane < end) ? srcs[chunk + lane] : 0;  // coalesced 256B

        uint4 v[8];
#pragma unroll
        for (int g = 0; g < 8; ++g) {
            int s = __shfl(es, g * 8 + slot, 64);
            if (g * 8 + slot < nrem)
                v[g] = *(const uint4*)(g_prev + (size_t)s * OUT_F + sub * 8);
        }
#pragma unroll
        for (int g = 0; g < 8; ++g) {
            if (g * 8 + slot < nrem) {
                acc[0] += __uint_as_float(v[g].x << 16);
                acc[1] += __uint_as_float(v[g].x & 0xffff0000u);
                acc[2] += __uint_as_float(v[g].y << 16);
                acc[3] += __uint_as_float(v[g].y & 0xffff0000u);
                acc[4] += __uint_as_float(v[g].z << 16);
                acc[5] += __uint_as_float(v[g].z & 0xffff0000u);
                acc[6] += __uint_as_float(v[g].w << 16);
                acc[7] += __uint_as_float(v[g].w & 0xffff0000u);
            }
        }
    }
#pragma unroll
    for (int off = 8; off <= 32; off <<= 1) {
#pragma unroll
        for (int j = 0; j < 8; ++j) acc[j] += __shfl_xor(acc[j], off, 64);
    }
    if (slot == 0) {          // lanes 0..7: write g_next row (bf16, 128B)
        float sc = dinv_in[node] * dinv_out[node];
        uint4 wv;
        wv.x = (unsigned)f2bf(sc * acc[0]) | ((unsigned)f2bf(sc * acc[1]) << 16);
        wv.y = (unsigned)f2bf(sc * acc[2]) | ((unsigned)f2bf(sc * acc[3]) << 16);
        wv.z = (unsigned)f2bf(sc * acc[4]) | ((unsigned)f2bf(sc * acc[5]) << 16);
        wv.w = (unsigned)f2bf(sc * acc[6]) | ((unsigned)f2bf(sc * acc[7]) << 16);
        *(uint4*)(g_next + (size_t)node * OUT_F + sub * 8) = wv;
    }
}

// ---------------------------------------------------------------------------
// Final gate-combine over all K+1 stored hop features.
// fn_k = g_k / dinv_out (wave-uniform); out = sum_k sigmoid(fn_k . s) * fn_k.
__global__ void __launch_bounds__(256) combine_kernel(
        const unsigned short* __restrict__ garena,
        const float* __restrict__ dinv_out,
        const float* __restrict__ sv,
        float* __restrict__ out) {
    int lane = threadIdx.x & 63;
    int node = blockIdx.x * 4 + (threadIdx.x >> 6);
    if (node >= N_NODES) return;
    float dv = dinv_out[node];
    float rinv = (dv > 0.0f) ? 1.0f / dv : 0.0f;
    float sl = sv[lane];
    size_t idx = (size_t)node * OUT_F + lane;
    const size_t gstride = (size_t)N_NODES * OUT_F;

    float o = 0.0f;
#pragma unroll
    for (int k = 0; k <= K_HOPS; ++k) {
        float fn = bf2f(garena[(size_t)k * gstride + idx]) * rinv;
        float p = fn * sl;
#pragma unroll
        for (int off = 1; off <= 32; off <<= 1) p += __shfl_xor(p, off, 64);
        float score = 1.0f / (1.0f + expf(-p));
        o = fmaf(score, fn, o);
    }
    out[idx] = o;
}

// ---------------------------------------------------------------------------
extern "C" void kernel_launch(void* const* d_in, const int* in_sizes, int n_in,
                              void* d_out, int out_size, void* d_ws, size_t ws_size,
                              hipStream_t stream) {
    const float* x  = (const float*)d_in[0];
    const void*  ei = d_in[1];
    const float* W1 = (const float*)d_in[2];
    const float* W2 = (const float*)d_in[3];
    const float* sv = (const float*)d_in[4];
    float* out = (float*)d_out;

    char* p = (char*)d_ws;
    auto alloc = [&](size_t bytes) -> char* {
        char* r = p;
        p += (bytes + 255) & ~(size_t)255;
        return r;
    };
    const size_t gstride = (size_t)N_NODES * OUT_F;
    unsigned short* garena = (unsigned short*)alloc(sizeof(unsigned short) * gstride * (K_HOPS + 1)); // 140.8 MB
    int*   src32     = (int*)alloc(sizeof(int) * N_EDGES);
    int*   dst32     = (int*)alloc(sizeof(int) * N_EDGES);
    // partials (16.8 MB) dead after hist_scan; entries_raw (12.8 MB) aliases it.
    char*  shared_region = alloc(sizeof(unsigned int) * 4 * HIST_BLOCKS * HIST_WORDS);
    unsigned int* partials = (unsigned int*)shared_region;
    int*   entries_raw = (int*)shared_region;
    int*   srcs      = (int*)alloc(sizeof(int) * N_EDGES);                      // 12.8 MB
    unsigned short* b1g = (unsigned short*)alloc(sizeof(unsigned short) * IN_F * HID);
    unsigned short* b2g = (unsigned short*)alloc(sizeof(unsigned short) * HID * OUT_F);
    float* dinv_out  = (float*)alloc(sizeof(float) * N_NODES);
    float* dinv_in   = (float*)alloc(sizeof(float) * N_NODES);
    int*   row_start = (int*)alloc(sizeof(int) * (N_NODES + 1));
    int*   bucket_cnt   = (int*)alloc(sizeof(int) * NBKT);
    int*   bucket_start = (int*)alloc(sizeof(int) * (NBKT + 1));
    int*   gcur      = (int*)alloc(sizeof(int) * NBKT);
    int*   flag      = (int*)alloc(256);

    hipMemsetAsync(flag, 0, sizeof(int), stream);
    hipMemsetAsync(bucket_cnt, 0, sizeof(int) * NBKT, stream);

    detect_i32_kernel<<<4, 256, 0, stream>>>((const unsigned int*)ei, flag);
    convert_kernel<<<(N_EDGES / 2 + 255) / 256, 256, 0, stream>>>(ei, flag, src32, dst32);
    wconv_kernel<<<(IN_F * HID + HID * OUT_F + 255) / 256, 256, 0, stream>>>(W1, W2, b1g, b2g);

    hist_kernel<<<dim3(HIST_BLOCKS, 4), 256, 0, stream>>>(src32, partials);
    hist_scan_kernel<<<(4 * HIST_WORDS + 255) / 256, 256, 0, stream>>>(partials, dinv_out);

    bucket_cnt_kernel<<<BKZ_BLOCKS, 256, 0, stream>>>(dst32, bucket_cnt);
    bucket_scan_kernel<<<1, 256, 0, stream>>>(bucket_cnt, bucket_start, gcur, row_start);
    bucketize_kernel<<<BKZ_BLOCKS, 256, 0, stream>>>(src32, dst32, gcur, entries_raw);

    hipFuncSetAttribute((const void*)sort_kernel,
                        hipFuncAttributeMaxDynamicSharedMemorySize, SORT_LDS_BYTES);
    sort_kernel<<<NBKT, 1024, SORT_LDS_BYTES, stream>>>(entries_raw, bucket_start,
                                                        srcs, row_start, dinv_in);

    int mlp_blocks = (N_NODES + 63) / 64;                   // 1563
    mlp_kernel<<<mlp_blocks, 256, 0, stream>>>(x, b1g, b2g, dinv_out, garena);

    int node_blocks = (N_NODES + 3) / 4;                    // 25000
    for (int hop = 1; hop <= K_HOPS; ++hop) {
        hop_kernel<<<node_blocks, 256, 0, stream>>>(garena + (size_t)(hop - 1) * gstride,
                                                    row_start, srcs, dinv_in, dinv_out,
                                                    garena + (size_t)hop * gstride);
    }
    combine_kernel<<<node_blocks, 256, 0, stream>>>(garena, dinv_out, sv, out);
}

// Round 13
// 759.928 us; speedup vs baseline: 3.0141x; 1.0526x over previous
//
#include <hip/hip_runtime.h>
#include <hip/hip_bf16.h>

#define N_NODES 100000
#define N_EDGES 3200000
#define IN_F 512
#define HID 64
#define OUT_F 64
#define K_HOPS 10

// src histogram geometry: 4 ranges of 32768 bins cover 131072 >= N_NODES
#define HIST_BLOCKS 64
#define HIST_BINS 32768
#define HIST_WORDS (HIST_BINS / 2)              // 16384 packed dual-uint16 words
#define EDGES_PER_HIST_BLOCK (N_EDGES / HIST_BLOCKS)  // 50000

// bucket geometry: 224 buckets x 448 nodes = 100352 >= N_NODES
#define NBKT 224
#define NBN  448
#define BKT_CAP 16384                            // mean 14286, sd ~120: safe
// bucketize pass
#define BKZ_BLOCKS 256
#define EDGES_PER_BKZ_BLOCK (N_EDGES / BKZ_BLOCKS)    // 12500
#define BKZ_BATCH 8192

typedef __attribute__((ext_vector_type(8))) short bf16x8;
typedef __attribute__((ext_vector_type(4))) float f32x4;

static __device__ __forceinline__ unsigned short f2bf(float f) {
    unsigned int u = __float_as_uint(f);
    u += 0x7FFFu + ((u >> 16) & 1u);            // round-to-nearest-even
    return (unsigned short)(u >> 16);
}
static __device__ __forceinline__ float bf2f(unsigned short s) {
    return __uint_as_float(((unsigned int)s) << 16);
}

// ---------------------------------------------------------------------------
__global__ void detect_i32_kernel(const unsigned int* ei_words, int* flag_is32) {
    int i = blockIdx.x * blockDim.x + threadIdx.x;  // 0..1023
    unsigned int w = ei_words[2 * i + 1];
    if (w != 0u) atomicOr(flag_is32, 1);
}

// Streaming int64->int32 conversion fused with the 224-bin bucket count.
// grid = BKZ_BLOCKS blocks; each handles EDGES_PER_BKZ_BLOCK/2 pairs.
__global__ void __launch_bounds__(256) convert_cnt_kernel(const void* ei_raw,
                                                          const int* flag_is32,
                                                          int* __restrict__ src32,
                                                          int* __restrict__ dst32,
                                                          int* __restrict__ bucket_cnt) {
    __shared__ int c[NBKT];
    int tid = threadIdx.x;
    if (tid < NBKT) c[tid] = 0;
    __syncthreads();
    const int pairs = EDGES_PER_BKZ_BLOCK / 2;          // 6250
    int base = blockIdx.x * pairs;
    int is32 = *flag_is32;
    for (int it = 0; it < pairs; it += 256) {
        int loc = it + tid;
        if (loc < pairs) {
            int t = base + loc;
            int2 sp, dp;
            if (is32) {
                const int2* ei = (const int2*)ei_raw;
                sp = ei[t];
                dp = ei[N_EDGES / 2 + t];
            } else {
                const longlong2* ei = (const longlong2*)ei_raw;
                longlong2 s = ei[t];
                longlong2 d = ei[N_EDGES / 2 + t];
                sp = make_int2((int)s.x, (int)s.y);
                dp = make_int2((int)d.x, (int)d.y);
            }
            *(int2*)(src32 + 2 * t) = sp;
            *(int2*)(dst32 + 2 * t) = dp;
            atomicAdd(&c[dp.x / NBN], 1);
            atomicAdd(&c[dp.y / NBN], 1);
        }
    }
    __syncthreads();
    if (tid < NBKT && c[tid] > 0) atomicAdd(&bucket_cnt[tid], c[tid]);
}

// Pre-swizzle W1/W2 into global B-fragment bf16 layout.
__global__ void __launch_bounds__(256) wconv_kernel(const float* __restrict__ W1,
                                                    const float* __restrict__ W2,
                                                    unsigned short* __restrict__ b1g,
                                                    unsigned short* __restrict__ b2g) {
    int o = blockIdx.x * blockDim.x + threadIdx.x;     // 0..36863
    int which = (o >= IN_F * HID);                      // 0: W1, 1: W2
    int oo = which ? (o - IN_F * HID) : o;
    int ko = oo & 7;
    int l = (oo >> 3) & 63;
    int kgs = l >> 4;
    int cm = l & 15;
    int tile = oo >> 9;
    int gt = tile >> 2;
    int nt = tile & 3;
    int k = gt * 32 + kgs * 8 + ko;
    int c = nt * 16 + cm;
    if (which) b2g[oo] = f2bf(W2[k * OUT_F + c]);
    else       b1g[oo] = f2bf(W1[k * HID + c]);
}

// Partial histograms of the src array in LDS (packed dual-uint16).
__global__ void __launch_bounds__(256) hist_kernel(const int* __restrict__ a,
                                                   unsigned int* __restrict__ partials) {
    __shared__ unsigned int cnt[HIST_WORDS];   // 64 KB
    int tid = threadIdx.x;
    for (int w = tid; w < HIST_WORDS; w += 256) cnt[w] = 0u;
    __syncthreads();

    int range = blockIdx.y;
    unsigned lo = (unsigned)(range * HIST_BINS);
    int beg = blockIdx.x * EDGES_PER_HIST_BLOCK;
    int end = beg + EDGES_PER_HIST_BLOCK;
    for (int i = beg + tid; i < end; i += 256) {
        unsigned v = (unsigned)a[i] - lo;
        if (v < HIST_BINS) atomicAdd(&cnt[v >> 1], 1u << ((v & 1u) * 16u));
    }
    __syncthreads();

    unsigned int* outp = partials + ((size_t)(blockIdx.y * HIST_BLOCKS + blockIdx.x)) * HIST_WORDS;
    for (int w = tid; w < HIST_WORDS / 4; w += 256)
        ((uint4*)outp)[w] = ((const uint4*)cnt)[w];
}

// Per-bin reduce over the 64 block-partials -> dinv_out.
__global__ void __launch_bounds__(256) hist_scan_kernel(const unsigned int* __restrict__ partials,
                                                        float* __restrict__ dinv) {
    int wg = blockIdx.x * blockDim.x + threadIdx.x;     // 0 .. 4*HIST_WORDS-1
    if (wg >= 4 * HIST_WORDS) return;
    int range = wg >> 14;
    int word = wg & (HIST_WORDS - 1);
    const unsigned int* base = partials + ((size_t)range * HIST_BLOCKS) * HIST_WORDS + word;
    unsigned lo = 0, hi = 0;
    for (int b = 0; b < HIST_BLOCKS; ++b) {
        unsigned c = base[(size_t)b * HIST_WORDS];
        lo += c & 0xffffu;
        hi += c >> 16;
    }
    int v0 = range * HIST_BINS + 2 * word;
    if (v0 < N_NODES) dinv[v0] = lo ? rsqrtf((float)lo) : 0.0f;
    int v1 = v0 + 1;
    if (v1 < N_NODES) dinv[v1] = hi ? rsqrtf((float)hi) : 0.0f;
}

// Scan bucket counts -> bucket_start[NBKT+1], gcur; also row_start[N]=E.
__global__ void __launch_bounds__(256) bucket_scan_kernel(const int* __restrict__ bucket_cnt,
                                                          int* __restrict__ bucket_start,
                                                          int* __restrict__ gcur,
                                                          int* __restrict__ row_start) {
    __shared__ int s[256];
    int t = threadIdx.x;
    int c = (t < NBKT) ? bucket_cnt[t] : 0;
    s[t] = c;
    __syncthreads();
    for (int off = 1; off < 256; off <<= 1) {
        int add = (t >= off) ? s[t - off] : 0;
        __syncthreads();
        s[t] += add;
        __syncthreads();
    }
    if (t < NBKT) {
        int excl = s[t] - c;
        bucket_start[t] = excl;
        gcur[t] = excl;
        if (t == NBKT - 1) {
            bucket_start[NBKT] = s[t];
            row_start[N_NODES] = s[t];
        }
    }
}

// Coarse bucketing with LDS-staged coalesced flushes. Entry = (src<<9)|dst_local.
__global__ void __launch_bounds__(256) bucketize_kernel(const int* __restrict__ src32,
                                                        const int* __restrict__ dst32,
                                                        int* __restrict__ gcur,
                                                        int* __restrict__ entries) {
    __shared__ unsigned int stag[BKZ_BATCH];     // 32 KB
    __shared__ unsigned char stagb[BKZ_BATCH];   // 8 KB
    __shared__ int cnt[256], sAr[256], ofs_l[256], gbase_l[256];

    int tid = threadIdx.x;
    int beg = blockIdx.x * EDGES_PER_BKZ_BLOCK;

    for (int bb = 0; bb < EDGES_PER_BKZ_BLOCK; bb += BKZ_BATCH) {
        int bn = min(BKZ_BATCH, EDGES_PER_BKZ_BLOCK - bb);
        cnt[tid] = 0;
        __syncthreads();

        unsigned pk[32];
#pragma unroll
        for (int j = 0; j < 32; ++j) {
            int loc = j * 256 + tid;
            pk[j] = 0xFFFFFFFFu;
            if (loc < bn) {
                int d = dst32[beg + bb + loc];
                int b = d / NBN;
                int dl = d - b * NBN;
                int off = atomicAdd(&cnt[b], 1);
                pk[j] = ((unsigned)b << 22) | ((unsigned)dl << 13) | (unsigned)off;
            }
        }
        __syncthreads();
        int c = cnt[tid];
        sAr[tid] = c;
        __syncthreads();
        for (int off = 1; off < 256; off <<= 1) {
            int add = (tid >= off) ? sAr[tid - off] : 0;
            __syncthreads();
            sAr[tid] += add;
            __syncthreads();
        }
        ofs_l[tid] = sAr[tid] - c;
        if (tid < NBKT && c > 0) gbase_l[tid] = atomicAdd(&gcur[tid], c);
        __syncthreads();

#pragma unroll
        for (int j = 0; j < 32; ++j) {
            int loc = j * 256 + tid;
            if (loc < bn && pk[j] != 0xFFFFFFFFu) {
                int s = src32[beg + bb + loc];
                int b = pk[j] >> 22;
                int dl = (pk[j] >> 13) & 511;
                int off = pk[j] & 8191;
                int pos = ofs_l[b] + off;
                stag[pos] = ((unsigned)s << 9) | (unsigned)dl;
                stagb[pos] = (unsigned char)b;
            }
        }
        __syncthreads();
        for (int i = tid; i < bn; i += 256) {
            int b = stagb[i];
            entries[gbase_l[b] + (i - ofs_l[b])] = (int)stag[i];
        }
        __syncthreads();
    }
}

// Per-bucket counting sort in LDS: produces dst-sorted src-only CSR and
// writes row_start + dinv_in for its 448 nodes.
#define SORT_LDS_BYTES ((2 * BKT_CAP + 512 + 512) * 4)    // 135,168 B
__global__ void __launch_bounds__(1024) sort_kernel(const int* __restrict__ entries,
                                                    const int* __restrict__ bucket_start,
                                                    int* __restrict__ srcs,
                                                    int* __restrict__ row_start,
                                                    float* __restrict__ dinv_in) {
    extern __shared__ int sbuf[];
    int* sin  = sbuf;                    // BKT_CAP
    int* sout = sbuf + BKT_CAP;          // BKT_CAP
    int* cnt  = sbuf + 2 * BKT_CAP;      // 512
    int* nsum = cnt + 512;               // 512
    int tid = threadIdx.x;
    int b = blockIdx.x;
    int ebeg = bucket_start[b];
    int eend = bucket_start[b + 1];
    int n = eend - ebeg;

    for (int i = tid; i < n; i += 1024) sin[i] = entries[ebeg + i];
    if (tid < 512) { cnt[tid] = 0; nsum[tid] = 0; }
    __syncthreads();
    for (int i = tid; i < n; i += 1024) {
        atomicAdd(&cnt[(unsigned)sin[i] & 511u], 1);
    }
    __syncthreads();
    int c = (tid < 512) ? cnt[tid] : 0;
    if (tid < 512) nsum[tid] = c;
    __syncthreads();
    for (int off = 1; off < 512; off <<= 1) {     // Hillis-Steele inclusive
        int v = (tid < 512 && tid >= off) ? nsum[tid - off] : 0;
        __syncthreads();
        if (tid < 512) nsum[tid] += v;
        __syncthreads();
    }
    if (tid < NBN) {
        int excl = nsum[tid] - c;
        cnt[tid] = excl;                          // reuse as cursor
        int node = b * NBN + tid;
        if (node < N_NODES) {
            row_start[node] = ebeg + excl;
            dinv_in[node] = c ? rsqrtf((float)c) : 0.0f;
        }
    }
    __syncthreads();
    for (int i = tid; i < n; i += 1024) {
        unsigned e = (unsigned)sin[i];
        int pos = atomicAdd(&cnt[e & 511u], 1);
        sout[pos] = (int)(e >> 9);
    }
    __syncthreads();
    for (int i = tid; i < n; i += 1024) srcs[ebeg + i] = sout[i];
}

// ---------------------------------------------------------------------------
// MFMA MLP: writes g0 = dinv_out * relu(relu(x@W1)@W2) in bf16 only.
__global__ void __launch_bounds__(256) mlp_kernel(const float* __restrict__ x,
                                                  const unsigned short* __restrict__ b1g,
                                                  const unsigned short* __restrict__ b2g,
                                                  const float* __restrict__ dinv_out,
                                                  unsigned short* __restrict__ g0) {
    __shared__ __align__(16) unsigned short a2s[4][2 * 64 * 8];   // 8 KB per-wave layer2 A

    int tid = threadIdx.x;
    int w = tid >> 6;
    int l = tid & 63;
    int kg = l >> 4;
    int m  = l & 15;
    int row0 = blockIdx.x * 64;
    int row = row0 + w * 16 + m;
    bool valid = row < N_NODES;
    const float* xp = x + (size_t)row * IN_F + kg * 8;

    f32x4 acc[4];
#pragma unroll
    for (int nt = 0; nt < 4; ++nt) acc[nt] = (f32x4){0.f, 0.f, 0.f, 0.f};

#pragma unroll 4
    for (int gt = 0; gt < 16; ++gt) {
        union { bf16x8 v; unsigned short u[8]; } a;
        if (valid) {
            const float* ap = xp + gt * 32;
            float4 u0 = *(const float4*)ap;
            float4 u1 = *(const float4*)(ap + 4);
            a.u[0] = f2bf(u0.x); a.u[1] = f2bf(u0.y);
            a.u[2] = f2bf(u0.z); a.u[3] = f2bf(u0.w);
            a.u[4] = f2bf(u1.x); a.u[5] = f2bf(u1.y);
            a.u[6] = f2bf(u1.z); a.u[7] = f2bf(u1.w);
        } else {
#pragma unroll
            for (int q = 0; q < 8; ++q) a.u[q] = 0;
        }
#pragma unroll
        for (int nt = 0; nt < 4; ++nt) {
            bf16x8 b = *(const bf16x8*)&b1g[((gt * 4 + nt) * 64 + l) * 8];
            acc[nt] = __builtin_amdgcn_mfma_f32_16x16x32_bf16(a.v, b, acc[nt], 0, 0, 0);
        }
    }

    // relu(h1) -> bf16 -> per-wave LDS restage into layer-2 A-frag layout
#pragma unroll
    for (int nt = 0; nt < 4; ++nt) {
#pragma unroll
        for (int reg = 0; reg < 4; ++reg) {
            float v = fmaxf(acc[nt][reg], 0.0f);
            int cc = nt * 16 + m;
            int r = kg * 4 + reg;
            a2s[w][((cc >> 5) * 64 + (((cc >> 3) & 3) * 16 + r)) * 8 + (cc & 7)] = f2bf(v);
        }
    }

    f32x4 acc2[4];
#pragma unroll
    for (int nt = 0; nt < 4; ++nt) acc2[nt] = (f32x4){0.f, 0.f, 0.f, 0.f};
#pragma unroll
    for (int t2 = 0; t2 < 2; ++t2) {
        bf16x8 a = *(const bf16x8*)&a2s[w][(t2 * 64 + l) * 8];
#pragma unroll
        for (int nt = 0; nt < 4; ++nt) {
            bf16x8 b = *(const bf16x8*)&b2g[((t2 * 4 + nt) * 64 + l) * 8];
            acc2[nt] = __builtin_amdgcn_mfma_f32_16x16x32_bf16(a, b, acc2[nt], 0, 0, 0);
        }
    }

#pragma unroll
    for (int reg = 0; reg < 4; ++reg) {
        int node = row0 + w * 16 + kg * 4 + reg;
        if (node < N_NODES) {
            float dv = dinv_out[node];
#pragma unroll
            for (int nt = 0; nt < 4; ++nt) {
                g0[(size_t)node * OUT_F + nt * 16 + m] =
                    f2bf(dv * fmaxf(acc2[nt][reg], 0.0f));
            }
        }
    }
}

// ---------------------------------------------------------------------------
// One hop, pure propagation, TWO nodes per wave (one per 32-lane half):
// 4 edge-slots x 8 feature-lanes per node, chunk = 32 edges -> 8 gathers
// in flight per lane at mean degree 32 (2x the 1-node/wave version).
// g_next = (dinv_in*dinv_out)[dst] * sum g_prev[src].
__global__ void __launch_bounds__(256) hop_kernel(
        const unsigned short* __restrict__ g_prev,
        const int* __restrict__ row_start,
        const int* __restrict__ srcs,
        const float* __restrict__ dinv_in,
        const float* __restrict__ dinv_out,
        unsigned short* __restrict__ g_next) {
    int lane = threadIdx.x & 63;
    int h = lane & 31;                   // index within half-wave
    int node = blockIdx.x * 8 + ((threadIdx.x >> 6) << 1) + (lane >> 5);
    if (node >= N_NODES) return;
    int beg = row_start[node];
    int end = row_start[node + 1];
    int slot = h >> 3;    // 0..3: edge slot within half
    int sub  = h & 7;     // feature group: features 8*sub..8*sub+7
    int hbase = lane & 32; // shuffle base of this half

    float acc[8];
#pragma unroll
    for (int j = 0; j < 8; ++j) acc[j] = 0.0f;

    for (int chunk = beg; chunk < end; chunk += 32) {
        int nrem = end - chunk;                       // half-wave-uniform
        int es = (chunk + h < end) ? srcs[chunk + h] : 0;  // coalesced 128B/half

        uint4 v[8];
#pragma unroll
        for (int g = 0; g < 8; ++g) {
            int s = __shfl(es, hbase + g * 4 + slot, 64);
            if (g * 4 + slot < nrem)
                v[g] = *(const uint4*)(g_prev + (size_t)s * OUT_F + sub * 8);
        }
#pragma unroll
        for (int g = 0; g < 8; ++g) {
            if (g * 4 + slot < nrem) {
                acc[0] += __uint_as_float(v[g].x << 16);
                acc[1] += __uint_as_float(v[g].x & 0xffff0000u);
                acc[2] += __uint_as_float(v[g].y << 16);
                acc[3] += __uint_as_float(v[g].y & 0xffff0000u);
                acc[4] += __uint_as_float(v[g].z << 16);
                acc[5] += __uint_as_float(v[g].z & 0xffff0000u);
                acc[6] += __uint_as_float(v[g].w << 16);
                acc[7] += __uint_as_float(v[g].w & 0xffff0000u);
            }
        }
    }
    // reduce the 4 edge-slots within each half (lane bits 3 and 4)
#pragma unroll
    for (int off = 8; off <= 16; off <<= 1) {
#pragma unroll
        for (int j = 0; j < 8; ++j) acc[j] += __shfl_xor(acc[j], off, 64);
    }
    if (slot == 0) {          // 8 lanes per half: write g_next row (bf16, 128B)
        float sc = dinv_in[node] * dinv_out[node];
        uint4 wv;
        wv.x = (unsigned)f2bf(sc * acc[0]) | ((unsigned)f2bf(sc * acc[1]) << 16);
        wv.y = (unsigned)f2bf(sc * acc[2]) | ((unsigned)f2bf(sc * acc[3]) << 16);
        wv.z = (unsigned)f2bf(sc * acc[4]) | ((unsigned)f2bf(sc * acc[5]) << 16);
        wv.w = (unsigned)f2bf(sc * acc[6]) | ((unsigned)f2bf(sc * acc[7]) << 16);
        *(uint4*)(g_next + (size_t)node * OUT_F + sub * 8) = wv;
    }
}

// ---------------------------------------------------------------------------
// Final gate-combine over all K+1 stored hop features.
// fn_k = g_k / dinv_out (wave-uniform); out = sum_k sigmoid(fn_k . s) * fn_k.
__global__ void __launch_bounds__(256) combine_kernel(
        const unsigned short* __restrict__ garena,
        const float* __restrict__ dinv_out,
        const float* __restrict__ sv,
        float* __restrict__ out) {
    int lane = threadIdx.x & 63;
    int node = blockIdx.x * 4 + (threadIdx.x >> 6);
    if (node >= N_NODES) return;
    float dv = dinv_out[node];
    float rinv = (dv > 0.0f) ? 1.0f / dv : 0.0f;
    float sl = sv[lane];
    size_t idx = (size_t)node * OUT_F + lane;
    const size_t gstride = (size_t)N_NODES * OUT_F;

    float o = 0.0f;
#pragma unroll
    for (int k = 0; k <= K_HOPS; ++k) {
        float fn = bf2f(garena[(size_t)k * gstride + idx]) * rinv;
        float p = fn * sl;
#pragma unroll
        for (int off = 1; off <= 32; off <<= 1) p += __shfl_xor(p, off, 64);
        float score = 1.0f / (1.0f + expf(-p));
        o = fmaf(score, fn, o);
    }
    out[idx] = o;
}

// ---------------------------------------------------------------------------
extern "C" void kernel_launch(void* const* d_in, const int* in_sizes, int n_in,
                              void* d_out, int out_size, void* d_ws, size_t ws_size,
                              hipStream_t stream) {
    const float* x  = (const float*)d_in[0];
    const void*  ei = d_in[1];
    const float* W1 = (const float*)d_in[2];
    const float* W2 = (const float*)d_in[3];
    const float* sv = (const float*)d_in[4];
    float* out = (float*)d_out;

    char* p = (char*)d_ws;
    auto alloc = [&](size_t bytes) -> char* {
        char* r = p;
        p += (bytes + 255) & ~(size_t)255;
        return r;
    };
    const size_t gstride = (size_t)N_NODES * OUT_F;
    unsigned short* garena = (unsigned short*)alloc(sizeof(unsigned short) * gstride * (K_HOPS + 1)); // 140.8 MB
    int*   src32     = (int*)alloc(sizeof(int) * N_EDGES);
    int*   dst32     = (int*)alloc(sizeof(int) * N_EDGES);
    // partials (16.8 MB) dead after hist_scan; entries_raw (12.8 MB) aliases it.
    char*  shared_region = alloc(sizeof(unsigned int) * 4 * HIST_BLOCKS * HIST_WORDS);
    unsigned int* partials = (unsigned int*)shared_region;
    int*   entries_raw = (int*)shared_region;
    int*   srcs      = (int*)alloc(sizeof(int) * N_EDGES);                      // 12.8 MB
    unsigned short* b1g = (unsigned short*)alloc(sizeof(unsigned short) * IN_F * HID);
    unsigned short* b2g = (unsigned short*)alloc(sizeof(unsigned short) * HID * OUT_F);
    float* dinv_out  = (float*)alloc(sizeof(float) * N_NODES);
    float* dinv_in   = (float*)alloc(sizeof(float) * N_NODES);
    int*   row_start = (int*)alloc(sizeof(int) * (N_NODES + 1));
    int*   bucket_cnt   = (int*)alloc(sizeof(int) * NBKT);
    int*   bucket_start = (int*)alloc(sizeof(int) * (NBKT + 1));
    int*   gcur      = (int*)alloc(sizeof(int) * NBKT);
    int*   flag      = (int*)alloc(256);

    hipMemsetAsync(flag, 0, sizeof(int), stream);
    hipMemsetAsync(bucket_cnt, 0, sizeof(int) * NBKT, stream);

    detect_i32_kernel<<<4, 256, 0, stream>>>((const unsigned int*)ei, flag);
    convert_cnt_kernel<<<BKZ_BLOCKS, 256, 0, stream>>>(ei, flag, src32, dst32, bucket_cnt);
    wconv_kernel<<<(IN_F * HID + HID * OUT_F + 255) / 256, 256, 0, stream>>>(W1, W2, b1g, b2g);

    hist_kernel<<<dim3(HIST_BLOCKS, 4), 256, 0, stream>>>(src32, partials);
    hist_scan_kernel<<<(4 * HIST_WORDS + 255) / 256, 256, 0, stream>>>(partials, dinv_out);

    bucket_scan_kernel<<<1, 256, 0, stream>>>(bucket_cnt, bucket_start, gcur, row_start);
    bucketize_kernel<<<BKZ_BLOCKS, 256, 0, stream>>>(src32, dst32, gcur, entries_raw);

    hipFuncSetAttribute((const void*)sort_kernel,
                        hipFuncAttributeMaxDynamicSharedMemorySize, SORT_LDS_BYTES);
    sort_kernel<<<NBKT, 1024, SORT_LDS_BYTES, stream>>>(entries_raw, bucket_start,
                                                        srcs, row_start, dinv_in);

    int mlp_blocks = (N_NODES + 63) / 64;                   // 1563
    mlp_kernel<<<mlp_blocks, 256, 0, stream>>>(x, b1g, b2g, dinv_out, garena);

    int hop_blocks = (N_NODES + 7) / 8;                     // 12500 (8 nodes/block)
    for (int hop = 1; hop <= K_HOPS; ++hop) {
        hop_kernel<<<hop_blocks, 256, 0, stream>>>(garena + (size_t)(hop - 1) * gstride,
                                                   row_start, srcs, dinv_in, dinv_out,
                                                   garena + (size_t)hop * gstride);
    }
    int node_blocks = (N_NODES + 3) / 4;                    // 25000
    combine_kernel<<<node_blocks, 256, 0, stream>>>(garena, dinv_out, sv, out);
}